// Round 1
// baseline (3230.448 us; speedup 1.0000x reference)
//
#include <hip/hip_runtime.h>
#include <cstdint>
#include <cstddef>

// ---------------------------------------------------------------------------
// ShuffleWindowAttention fused kernel for MI355X (gfx950)
// B=4, N=50176, C=512, WS=49, windows-per-batch w=1024, NH=8, hd=64
// Window wi of batch b holds tokens { s*1024 + wi : s in [0,49) }.
// Per window:  qkv = xw @ Wqkv^T (+b)  -> per-head attention -> @ Wproj^T (+b)
// All GEMMs in bf16 MFMA (16x16x32), fp32 accumulate. Softmax scale folded
// into Wq/bq at weight-conversion time (scale = 64^-0.5 = 0.125 exactly).
// ---------------------------------------------------------------------------

typedef __bf16 bf16x8 __attribute__((ext_vector_type(8)));
typedef __bf16 bf16x4 __attribute__((ext_vector_type(4)));
typedef float  f32x4  __attribute__((ext_vector_type(4)));

#define MFMA_BF16(a, b, c) __builtin_amdgcn_mfma_f32_16x16x32_bf16((a), (b), (c), 0, 0, 0)

// element-index XOR swizzle: spreads 8 consecutive rows across the 32 LDS banks
// (byte ^= ((row&7)<<4)  ==  elem ^= ((row&7)<<3) for 2-byte elements)
static __device__ __forceinline__ int swzi(int row, int col) {
  return col ^ ((row & 7) << 3);
}

// ---------------------------------------------------------------------------
// Weight prep: fp32 -> bf16, fold 0.125 attention scale into the Q block.
// ---------------------------------------------------------------------------
__global__ void prep_weights(const float* __restrict__ wqkv,
                             const float* __restrict__ bqkv,
                             const float* __restrict__ wproj,
                             __bf16* __restrict__ wqkv_bf,
                             __bf16* __restrict__ wproj_bf,
                             float* __restrict__ bq_s) {
  const int stride = gridDim.x * blockDim.x;
  const int t0 = blockIdx.x * blockDim.x + threadIdx.x;
  for (int i = t0; i < 1536 * 512; i += stride) {
    float v = wqkv[i];
    if (i < 512 * 512) v *= 0.125f;          // q rows scaled
    wqkv_bf[i] = (__bf16)v;
  }
  for (int i = t0; i < 512 * 512; i += stride) wproj_bf[i] = (__bf16)wproj[i];
  for (int i = t0; i < 1536; i += stride)      bq_s[i] = (i < 512 ? 0.125f : 1.0f) * bqkv[i];
}

// ---------------------------------------------------------------------------
// Fused per-window kernel. One block (256 thr = 4 waves) per window.
// M=49 handled by overlapping 16-row M-tiles at offsets {0,16,32,33}
// (overlap rows recompute identical values -> benign).
// LDS = 77,184 B  ->  2 blocks/CU.
// ---------------------------------------------------------------------------
__launch_bounds__(256, 2)
__global__ void swin_attn_fused(const float* __restrict__ x,
                                const __bf16* __restrict__ wqkv_bf,
                                const float* __restrict__ bq_s,
                                const __bf16* __restrict__ wproj_bf,
                                const float* __restrict__ bproj,
                                float* __restrict__ out) {
  __shared__ __align__(16) __bf16 s_xw[49 * 512];  // x window, bf16, swizzled
  __shared__ __align__(16) __bf16 s_q [49 * 64];   // per-head q (scaled)
  __shared__ __align__(16) __bf16 s_k [49 * 64];   // per-head k
  __shared__ __align__(16) __bf16 s_vT[64 * 64];   // per-head v TRANSPOSED [col][row]
  __shared__ __align__(16) __bf16 s_p [49 * 64];   // P (softmax), then reused for O

  const int tid  = threadIdx.x;
  const int lane = tid & 63;
  const int wv   = tid >> 6;           // wave 0..3
  const int l15  = lane & 15;
  const int kg   = (lane >> 4) * 8;    // k-group base for A/B fragments
  const int r4   = (lane >> 4) * 4;    // row-group base for C/D fragments

  const int blk = blockIdx.x;
  const int b   = blk >> 10;           // batch
  const int wi  = blk & 1023;          // window within batch

  const int MOFF[4] = {0, 16, 32, 33}; // overlapping M-tile row offsets (cover 0..48)
  const float NEG_INF = -__builtin_inff();

  // ---- init: zero v^T (rows 49..63 of k-dim must be 0; zero it all) ----
  for (int i = tid; i < 64 * 64; i += 256) s_vT[i] = (__bf16)0.0f;

  // ---- stage x window -> bf16 LDS (49 rows x 512, swizzled) ----
  const float* xwin = x + ((size_t)b * 50176 + (size_t)wi) * 512;
  for (int idx = tid; idx < 49 * 128; idx += 256) {
    const int row = idx >> 7;
    const int c4  = (idx & 127) * 4;
    const float4 v = *(const float4*)(xwin + (size_t)row * (1024 * 512) + c4);
    bf16x4 t;
    t.x = (__bf16)v.x; t.y = (__bf16)v.y; t.z = (__bf16)v.z; t.w = (__bf16)v.w;
    *(bf16x4*)&s_xw[row * 512 + swzi(row, c4)] = t;
  }

  // ---- proj accumulators: final[rows 0..48 (tiled)][wv*128 .. wv*128+128) ----
  f32x4 accF[4][8];
  const f32x4 zf = {0.f, 0.f, 0.f, 0.f};
#pragma unroll
  for (int m = 0; m < 4; ++m)
#pragma unroll
    for (int n = 0; n < 8; ++n) accF[m][n] = zf;

  __syncthreads();

  for (int h = 0; h < 8; ++h) {
    // ================= Phase A: q|k|v = xw @ Wqkv_h^T  =================
    // output cols 0..191 (q:0-63, k:64-127, v:128-191); wave owns 48 cols.
    f32x4 accA[4][3];
#pragma unroll
    for (int m = 0; m < 4; ++m)
#pragma unroll
      for (int n = 0; n < 3; ++n) accA[m][n] = zf;

    const __bf16* pB[3];
    float biasv[3];
#pragma unroll
    for (int nt = 0; nt < 3; ++nt) {
      const int c  = wv * 48 + nt * 16 + l15;
      const int wr = (c < 64) ? (h * 64 + c)
                   : (c < 128) ? (512 + h * 64 + (c - 64))
                               : (1024 + h * 64 + (c - 128));
      pB[nt]    = wqkv_bf + (size_t)wr * 512 + kg;
      biasv[nt] = bq_s[wr];
    }

#pragma unroll
    for (int ks = 0; ks < 16; ++ks) {
      bf16x8 a[4], bb[3];
#pragma unroll
      for (int mt = 0; mt < 4; ++mt) {
        const int row = MOFF[mt] + l15;
        a[mt] = *(const bf16x8*)&s_xw[row * 512 + swzi(row, ks * 32 + kg)];
      }
#pragma unroll
      for (int nt = 0; nt < 3; ++nt) bb[nt] = *(const bf16x8*)(pB[nt] + ks * 32);
#pragma unroll
      for (int mt = 0; mt < 4; ++mt)
#pragma unroll
        for (int nt = 0; nt < 3; ++nt)
          accA[mt][nt] = MFMA_BF16(a[mt], bb[nt], accA[mt][nt]);
    }

    // epilogue: + bias, bf16, scatter into s_q / s_k / s_vT(transposed)
#pragma unroll
    for (int nt = 0; nt < 3; ++nt) {
      const int c = wv * 48 + nt * 16 + l15;
#pragma unroll
      for (int mt = 0; mt < 4; ++mt) {
#pragma unroll
        for (int r = 0; r < 4; ++r) {
          const int row = MOFF[mt] + r4 + r;
          const __bf16 bvv = (__bf16)(accA[mt][nt][r] + biasv[nt]);
          if (c < 64)       s_q[row * 64 + swzi(row, c)] = bvv;
          else if (c < 128) s_k[row * 64 + swzi(row, c - 64)] = bvv;
          else {
            const int vr = c - 128;                 // v column -> vT row
            s_vT[vr * 64 + swzi(vr, row)] = bvv;    // transposed store
          }
        }
      }
    }
    __syncthreads();  // bar1: q/k/vT complete

    // ================= Phase B: S = q k^T  + in-register softmax =========
    const int R = MOFF[wv];  // this wave's 16 S-rows
    bf16x8 aq[2], bk[4][2];
#pragma unroll
    for (int ks2 = 0; ks2 < 2; ++ks2) {
      const int row = R + l15;
      aq[ks2] = *(const bf16x8*)&s_q[row * 64 + swzi(row, ks2 * 32 + kg)];
    }
#pragma unroll
    for (int nt = 0; nt < 4; ++nt) {
      const int row = MOFF[nt] + l15;   // S columns tiled like rows (0,16,32,33)
#pragma unroll
      for (int ks2 = 0; ks2 < 2; ++ks2)
        bk[nt][ks2] = *(const bf16x8*)&s_k[row * 64 + swzi(row, ks2 * 32 + kg)];
    }
    f32x4 accS[4];
#pragma unroll
    for (int n = 0; n < 4; ++n) accS[n] = zf;
#pragma unroll
    for (int ks2 = 0; ks2 < 2; ++ks2)
#pragma unroll
      for (int nt = 0; nt < 4; ++nt)
        accS[nt] = MFMA_BF16(aq[ks2], bk[nt][ks2], accS[nt]);

    // softmax over cols {0..48}; nt=3 tile covers cols 33..48 -> only col 48 (l15==15) is new
#pragma unroll
    for (int r = 0; r < 4; ++r) {
      const int row = R + r4 + r;
      const float sv0 = accS[0][r];
      const float sv1 = accS[1][r];
      const float sv2 = accS[2][r];
      const float sv3 = (l15 == 15) ? accS[3][r] : NEG_INF;
      float m = fmaxf(fmaxf(sv0, sv1), fmaxf(sv2, sv3));
      m = fmaxf(m, __shfl_xor(m, 1));
      m = fmaxf(m, __shfl_xor(m, 2));
      m = fmaxf(m, __shfl_xor(m, 4));
      m = fmaxf(m, __shfl_xor(m, 8));
      const float e0 = __expf(sv0 - m);
      const float e1 = __expf(sv1 - m);
      const float e2 = __expf(sv2 - m);
      const float e3 = __expf(sv3 - m);   // 0 for masked lanes
      float s = e0 + e1 + e2 + e3;
      s += __shfl_xor(s, 1);
      s += __shfl_xor(s, 2);
      s += __shfl_xor(s, 4);
      s += __shfl_xor(s, 8);
      const float inv = 1.0f / s;
      s_p[row * 64 + swzi(row, 0  + l15)] = (__bf16)(e0 * inv);
      s_p[row * 64 + swzi(row, 16 + l15)] = (__bf16)(e1 * inv);
      s_p[row * 64 + swzi(row, 32 + l15)] = (__bf16)(e2 * inv);
      if (l15 == 15) s_p[row * 64 + swzi(row, 48)] = (__bf16)(e3 * inv);
      if (l15 < 15)  s_p[row * 64 + swzi(row, 49 + l15)] = (__bf16)0.0f;  // K-pad of PV
    }

    // ================= Phase C: O = P @ V =================
    bf16x8 ap[2], bv2[4][2];
#pragma unroll
    for (int ks2 = 0; ks2 < 2; ++ks2) {
      const int row = R + l15;
      ap[ks2] = *(const bf16x8*)&s_p[row * 64 + swzi(row, ks2 * 32 + kg)];
    }
#pragma unroll
    for (int nt = 0; nt < 4; ++nt) {
      const int row = nt * 16 + l15;      // vT row = output col (0..63)
#pragma unroll
      for (int ks2 = 0; ks2 < 2; ++ks2)
        bv2[nt][ks2] = *(const bf16x8*)&s_vT[row * 64 + swzi(row, ks2 * 32 + kg)];
    }
    __syncthreads();  // bar_c: everyone has read P before O overwrites it

    f32x4 accO[4];
#pragma unroll
    for (int n = 0; n < 4; ++n) accO[n] = zf;
#pragma unroll
    for (int ks2 = 0; ks2 < 2; ++ks2)
#pragma unroll
      for (int nt = 0; nt < 4; ++nt)
        accO[nt] = MFMA_BF16(ap[ks2], bv2[nt][ks2], accO[nt]);

    // write O (bf16) into s_p (own rows, all 64 cols)
#pragma unroll
    for (int nt = 0; nt < 4; ++nt) {
#pragma unroll
      for (int r = 0; r < 4; ++r) {
        const int row = R + r4 + r;
        s_p[row * 64 + swzi(row, nt * 16 + l15)] = (__bf16)accO[nt][r];
      }
    }
    __syncthreads();  // bar2: O complete for all rows

    // ================= Phase D: accF += O @ Wproj_h^T ====================
#pragma unroll
    for (int ks2 = 0; ks2 < 2; ++ks2) {
      bf16x8 ao[4], bw[8];
#pragma unroll
      for (int mt = 0; mt < 4; ++mt) {
        const int row = MOFF[mt] + l15;
        ao[mt] = *(const bf16x8*)&s_p[row * 64 + swzi(row, ks2 * 32 + kg)];
      }
#pragma unroll
      for (int nt = 0; nt < 8; ++nt) {
        const int cc = wv * 128 + nt * 16 + l15;
        bw[nt] = *(const bf16x8*)(wproj_bf + (size_t)cc * 512 + h * 64 + ks2 * 32 + kg);
      }
#pragma unroll
      for (int mt = 0; mt < 4; ++mt)
#pragma unroll
        for (int nt = 0; nt < 8; ++nt)
          accF[mt][nt] = MFMA_BF16(ao[mt], bw[nt], accF[mt][nt]);
    }
  }  // head loop

  // ---- final write (un-shuffle): out[b][row*1024 + wi][col] ----
#pragma unroll
  for (int nt = 0; nt < 8; ++nt) {
    const int cc = wv * 128 + nt * 16 + l15;
    const float bp = bproj[cc];
#pragma unroll
    for (int mt = 0; mt < 4; ++mt) {
#pragma unroll
      for (int r = 0; r < 4; ++r) {
        const int row = MOFF[mt] + r4 + r;
        if (mt < 3 || (r4 + r) == 15) {  // skip duplicated overlap rows (33..47 of tile 3)
          out[((size_t)b * 50176 + (size_t)row * 1024 + (size_t)wi) * 512 + cc] =
              accF[mt][nt][r] + bp;
        }
      }
    }
  }
}

// ---------------------------------------------------------------------------
extern "C" void kernel_launch(void* const* d_in, const int* in_sizes, int n_in,
                              void* d_out, int out_size, void* d_ws, size_t ws_size,
                              hipStream_t stream) {
  const float* x      = (const float*)d_in[0];
  const float* w_qkv  = (const float*)d_in[1];
  const float* b_qkv  = (const float*)d_in[2];
  const float* w_proj = (const float*)d_in[3];
  const float* b_proj = (const float*)d_in[4];
  float* outp = (float*)d_out;

  // workspace layout: wqkv_bf [1536*512] bf16 | wproj_bf [512*512] bf16 | bq_s [1536] f32
  __bf16* wqkv_bf  = (__bf16*)d_ws;
  __bf16* wproj_bf = wqkv_bf + 1536 * 512;
  float*  bq_s     = (float*)(wproj_bf + 512 * 512);

  prep_weights<<<1024, 256, 0, stream>>>(w_qkv, b_qkv, w_proj, wqkv_bf, wproj_bf, bq_s);
  swin_attn_fused<<<4096, 256, 0, stream>>>(x, wqkv_bf, bq_s, wproj_bf, b_proj, outp);
}

// Round 2
// 1645.775 us; speedup vs baseline: 1.9629x; 1.9629x over previous
//
#include <hip/hip_runtime.h>
#include <cstdint>
#include <cstddef>

// ---------------------------------------------------------------------------
// ShuffleWindowAttention, MI355X (gfx950)
// B=4, N=50176, C=512, WS=49, w=1024 windows/batch, NH=8, hd=64
// Split pipeline: prep -> QKV GEMM -> windowed attention -> proj GEMM.
// Fallback to the round-1 fused kernel if ws_size is too small.
// ---------------------------------------------------------------------------

typedef __bf16 bf16x8 __attribute__((ext_vector_type(8)));
typedef __bf16 bf16x4 __attribute__((ext_vector_type(4)));
typedef float  f32x4  __attribute__((ext_vector_type(4)));

#define MFMA_BF16(a, b, c) __builtin_amdgcn_mfma_f32_16x16x32_bf16((a), (b), (c), 0, 0, 0)

static __device__ __forceinline__ int swzi(int row, int col) {
  return col ^ ((row & 7) << 3);   // element-index XOR swizzle (2B elems)
}

typedef __attribute__((address_space(1))) const void gconst_t;
typedef __attribute__((address_space(3))) void lds_t;
static __device__ __forceinline__ void gload16(const void* g, void* l) {
  __builtin_amdgcn_global_load_lds((gconst_t*)g, (lds_t*)l, 16, 0, 0);
}

// ---------------------------------------------------------------------------
// Weight prep: fp32 -> bf16, fold 0.125 attention scale into the Q block.
// ---------------------------------------------------------------------------
__global__ void prep_weights(const float* __restrict__ wqkv,
                             const float* __restrict__ bqkv,
                             const float* __restrict__ wproj,
                             __bf16* __restrict__ wqkv_bf,
                             __bf16* __restrict__ wproj_bf,
                             float* __restrict__ bq_s) {
  const int stride = gridDim.x * blockDim.x;
  const int t0 = blockIdx.x * blockDim.x + threadIdx.x;
  for (int i = t0; i < 1536 * 512; i += stride) {
    float v = wqkv[i];
    if (i < 512 * 512) v *= 0.125f;
    wqkv_bf[i] = (__bf16)v;
  }
  for (int i = t0; i < 512 * 512; i += stride) wproj_bf[i] = (__bf16)wproj[i];
  for (int i = t0; i < 1536; i += stride)      bq_s[i] = (i < 512 ? 0.125f : 1.0f) * bqkv[i];
}

// ---------------------------------------------------------------------------
// GEMM: C[M][N] = A[M][512] @ B[N][512]^T + bias.  128x128 tile, 4 waves,
// BK=32, double-buffered LDS, m97-style 2-phase.  A either fp32 (reg-staged
// cvt) or bf16 (global_load_lds).  Out either bf16 or fp32.
// ---------------------------------------------------------------------------
template<bool A_F32, bool OUT_F32>
__launch_bounds__(256)
__global__ void gemm_bt(const void* __restrict__ Av,
                        const __bf16* __restrict__ Bw,   // [N][512]
                        const float* __restrict__ bias,  // [N]
                        void* __restrict__ Cv,
                        int Mtiles, int Ntiles) {
  __shared__ __align__(16) __bf16 sA[2][128 * 32];
  __shared__ __align__(16) __bf16 sB[2][128 * 32];

  const int tid  = threadIdx.x;
  const int lane = tid & 63;
  const int l15  = lane & 15;
  const int kg   = ((lane >> 4) & 3) * 8;
  const int r4   = ((lane >> 4) & 3) * 4;
  const int wv   = tid >> 6, wm = wv >> 1, wn = wv & 1;

  const int nwg = Mtiles * Ntiles;
  const int cpx = nwg >> 3;                       // nwg % 8 == 0 for our grids
  const int wg  = (blockIdx.x & 7) * cpx + (blockIdx.x >> 3);
  const int mt  = wg % Mtiles;
  const int nt  = wg / Mtiles;                    // N-outer: B-panel L2 reuse
  const size_t m0 = (size_t)mt * 128;
  const int    n0 = nt * 128;

  const float*  Af = (const float*)Av;
  const __bf16* Ab = (const __bf16*)Av;

  // gload_lds mapping (linear in tid): row = j*64 + tid>>2, col8 = (tid&3)*8
  const int srow  = tid >> 2;
  const int scol8 = (tid & 3) * 8;
  // fp32-A reg-stage mapping: row = tid&127 (2-way-bank-free ds_write), seg
  const int arow = tid & 127;
  const int aseg = (tid >> 7) * 16;

  f32x4 acc[4][4];
  const f32x4 zf = {0.f, 0.f, 0.f, 0.f};
#pragma unroll
  for (int i = 0; i < 4; ++i)
#pragma unroll
    for (int j = 0; j < 4; ++j) acc[i][j] = zf;

  // ---- prologue: stage k-step 0 into buf 0 ----
  {
#pragma unroll
    for (int j = 0; j < 2; ++j)
      gload16(Bw + ((size_t)(n0 + j * 64 + srow)) * 512 + scol8,
              &sB[0][0] + (size_t)tid * 8 + j * 2048);
    if (A_F32) {
      float4 a4[4];
#pragma unroll
      for (int q = 0; q < 4; ++q)
        a4[q] = *(const float4*)(Af + (m0 + arow) * 512 + aseg + q * 4);
#pragma unroll
      for (int q = 0; q < 2; ++q) {
        bf16x8 t;
        t[0] = (__bf16)a4[q*2].x; t[1] = (__bf16)a4[q*2].y;
        t[2] = (__bf16)a4[q*2].z; t[3] = (__bf16)a4[q*2].w;
        t[4] = (__bf16)a4[q*2+1].x; t[5] = (__bf16)a4[q*2+1].y;
        t[6] = (__bf16)a4[q*2+1].z; t[7] = (__bf16)a4[q*2+1].w;
        *(bf16x8*)&sA[0][arow * 32 + aseg + q * 8] = t;
      }
    } else {
#pragma unroll
      for (int j = 0; j < 2; ++j)
        gload16(Ab + (m0 + j * 64 + srow) * 512 + scol8,
                &sA[0][0] + (size_t)tid * 8 + j * 2048);
    }
  }
  __syncthreads();

  int buf = 0;
  for (int kt = 0; kt < 16; ++kt) {
    const int k1 = (kt + 1) * 32;
    float4 a4[4];
    if (kt < 15) {
#pragma unroll
      for (int j = 0; j < 2; ++j)
        gload16(Bw + ((size_t)(n0 + j * 64 + srow)) * 512 + k1 + scol8,
                &sB[buf ^ 1][0] + (size_t)tid * 8 + j * 2048);
      if (A_F32) {
#pragma unroll
        for (int q = 0; q < 4; ++q)
          a4[q] = *(const float4*)(Af + (m0 + arow) * 512 + k1 + aseg + q * 4);
      } else {
#pragma unroll
        for (int j = 0; j < 2; ++j)
          gload16(Ab + (m0 + j * 64 + srow) * 512 + k1 + scol8,
                  &sA[buf ^ 1][0] + (size_t)tid * 8 + j * 2048);
      }
    }
    // compute current buffer
    bf16x8 af[4], bfr[4];
#pragma unroll
    for (int m = 0; m < 4; ++m)
      af[m] = *(const bf16x8*)&sA[buf][(wm * 64 + m * 16 + l15) * 32 + kg];
#pragma unroll
    for (int n = 0; n < 4; ++n)
      bfr[n] = *(const bf16x8*)&sB[buf][(wn * 64 + n * 16 + l15) * 32 + kg];
#pragma unroll
    for (int m = 0; m < 4; ++m)
#pragma unroll
      for (int n = 0; n < 4; ++n)
        acc[m][n] = MFMA_BF16(af[m], bfr[n], acc[m][n]);

    if (A_F32 && kt < 15) {
#pragma unroll
      for (int q = 0; q < 2; ++q) {
        bf16x8 t;
        t[0] = (__bf16)a4[q*2].x; t[1] = (__bf16)a4[q*2].y;
        t[2] = (__bf16)a4[q*2].z; t[3] = (__bf16)a4[q*2].w;
        t[4] = (__bf16)a4[q*2+1].x; t[5] = (__bf16)a4[q*2+1].y;
        t[6] = (__bf16)a4[q*2+1].z; t[7] = (__bf16)a4[q*2+1].w;
        *(bf16x8*)&sA[buf ^ 1][arow * 32 + aseg + q * 8] = t;
      }
    }
    __syncthreads();
    buf ^= 1;
  }

  // ---- epilogue ----
  const int Nld = Ntiles * 128;
#pragma unroll
  for (int n = 0; n < 4; ++n) {
    const int col = n0 + wn * 64 + n * 16 + l15;
    const float bb = bias[col];
#pragma unroll
    for (int m = 0; m < 4; ++m) {
#pragma unroll
      for (int r = 0; r < 4; ++r) {
        const size_t row = m0 + wm * 64 + m * 16 + r4 + r;
        const float v = acc[m][n][r] + bb;
        if (OUT_F32) ((float*)Cv)[row * (size_t)Nld + col] = v;
        else         ((__bf16*)Cv)[row * (size_t)Nld + col] = (__bf16)v;
      }
    }
  }
}

// ---------------------------------------------------------------------------
// Windowed attention: one block (8 waves) per window, wave = head.
// qkv[token][1536] bf16 in;  O[token][512] bf16 out.
// ---------------------------------------------------------------------------
__launch_bounds__(512)
__global__ void attn_win(const __bf16* __restrict__ qkv, __bf16* __restrict__ O) {
  __shared__ __align__(16) __bf16 vT[8 * 64 * 64];   // [h][n][k ^ swz(n)]
  __shared__ __align__(16) __bf16 sP[8][16 * 64];    // per-wave P tile

  const int tid  = threadIdx.x;
  const int lane = tid & 63;
  const int h    = tid >> 6;                 // wave = head
  const int l15  = lane & 15;
  const int kg   = ((lane >> 4) & 3) * 8;
  const int r4   = ((lane >> 4) & 3) * 4;

  const int blk = blockIdx.x;
  const int b   = blk >> 10;
  const int wi  = blk & 1023;
  const size_t tokbase = (size_t)b * 50176 + wi;   // token(s) = tokbase + s*1024

  const int MOFF[4] = {0, 16, 32, 33};
  const float NEG_INF = -__builtin_inff();

  // ---- issue q,k fragment loads early (overlap with V staging) ----
  bf16x8 aq[4][2], bk[4][2];
#pragma unroll
  for (int mt = 0; mt < 4; ++mt) {
    const size_t tok = tokbase + (size_t)(MOFF[mt] + l15) * 1024;
#pragma unroll
    for (int ks = 0; ks < 2; ++ks) {
      aq[mt][ks] = *(const bf16x8*)(qkv + tok * 1536 +       h * 64 + ks * 32 + kg);
      bk[mt][ks] = *(const bf16x8*)(qkv + tok * 1536 + 512 + h * 64 + ks * 32 + kg);
    }
  }

  // ---- zero vT pad rows k = 49..63 ----
  for (int i = tid; i < 8 * 64 * 16; i += 512) {
    const int k = 48 + (i & 15);
    if (k != 48) {
      const int n  = (i >> 4) & 63;
      const int hh = i >> 10;
      vT[hh * 4096 + n * 64 + (k ^ ((n & 7) << 3))] = (__bf16)0.0f;
    }
  }
  // ---- stage V transposed (+swizzled) ----
  for (int i = tid; i < 49 * 64; i += 512) {
    const int s  = i >> 6;
    const int c8 = (i & 63) * 8;
    bf16x8 v8 = *(const bf16x8*)(qkv + (tokbase + (size_t)s * 1024) * 1536 + 1024 + c8);
    const int hh = c8 >> 6;
#pragma unroll
    for (int j = 0; j < 8; ++j) {
      const int n = (c8 & 63) + j;
      vT[hh * 4096 + n * 64 + (s ^ ((n & 7) << 3))] = v8[j];
    }
  }
  __syncthreads();

  // ---- V fragments (conflict-free via swizzle) ----
  bf16x8 bv[4][2];
#pragma unroll
  for (int ntv = 0; ntv < 4; ++ntv) {
    const int n = ntv * 16 + l15;
#pragma unroll
    for (int ks = 0; ks < 2; ++ks)
      bv[ntv][ks] = *(const bf16x8*)&vT[h * 4096 + n * 64 + ((ks * 32 + kg) ^ ((n & 7) << 3))];
  }

  // ---- S = q k^T (all 4 row-tiles x 4 col-tiles) ----
  f32x4 accS[4][4];
  const f32x4 zf = {0.f, 0.f, 0.f, 0.f};
#pragma unroll
  for (int m = 0; m < 4; ++m)
#pragma unroll
    for (int n = 0; n < 4; ++n) accS[m][n] = zf;
#pragma unroll
  for (int ks = 0; ks < 2; ++ks)
#pragma unroll
    for (int m = 0; m < 4; ++m)
#pragma unroll
      for (int n = 0; n < 4; ++n)
        accS[m][n] = MFMA_BF16(aq[m][ks], bk[n][ks], accS[m][n]);

  // ---- per row-tile: softmax -> P (LDS) -> PV -> store O ----
#pragma unroll
  for (int mt = 0; mt < 4; ++mt) {
#pragma unroll
    for (int r = 0; r < 4; ++r) {
      const int prow = r4 + r;
      const float sv0 = accS[mt][0][r];
      const float sv1 = accS[mt][1][r];
      const float sv2 = accS[mt][2][r];
      const float sv3 = (l15 == 15) ? accS[mt][3][r] : NEG_INF;
      float mx = fmaxf(fmaxf(sv0, sv1), fmaxf(sv2, sv3));
      mx = fmaxf(mx, __shfl_xor(mx, 1));
      mx = fmaxf(mx, __shfl_xor(mx, 2));
      mx = fmaxf(mx, __shfl_xor(mx, 4));
      mx = fmaxf(mx, __shfl_xor(mx, 8));
      const float e0 = __expf(sv0 - mx);
      const float e1 = __expf(sv1 - mx);
      const float e2 = __expf(sv2 - mx);
      const float e3 = __expf(sv3 - mx);      // 0 for masked lanes
      float sum = e0 + e1 + e2 + e3;
      sum += __shfl_xor(sum, 1);
      sum += __shfl_xor(sum, 2);
      sum += __shfl_xor(sum, 4);
      sum += __shfl_xor(sum, 8);
      const float inv = 1.0f / sum;
      sP[h][prow * 64 + swzi(prow, 0  + l15)] = (__bf16)(e0 * inv);
      sP[h][prow * 64 + swzi(prow, 16 + l15)] = (__bf16)(e1 * inv);
      sP[h][prow * 64 + swzi(prow, 32 + l15)] = (__bf16)(e2 * inv);
      if (l15 == 15) sP[h][prow * 64 + swzi(prow, 48)] = (__bf16)(e3 * inv);
      if (l15 < 15)  sP[h][prow * 64 + swzi(prow, 49 + l15)] = (__bf16)0.0f;
    }
    // PV (same-wave DS ordering: write then read is in-order)
    bf16x8 ap[2];
#pragma unroll
    for (int ks = 0; ks < 2; ++ks)
      ap[ks] = *(const bf16x8*)&sP[h][l15 * 64 + swzi(l15, ks * 32 + kg)];
    f32x4 accO[4];
#pragma unroll
    for (int n = 0; n < 4; ++n) accO[n] = zf;
#pragma unroll
    for (int ks = 0; ks < 2; ++ks)
#pragma unroll
      for (int n = 0; n < 4; ++n)
        accO[n] = MFMA_BF16(ap[ks], bv[n][ks], accO[n]);
#pragma unroll
    for (int n = 0; n < 4; ++n) {
#pragma unroll
      for (int r = 0; r < 4; ++r) {
        const int row = MOFF[mt] + r4 + r;
        O[(tokbase + (size_t)row * 1024) * 512 + h * 64 + n * 16 + l15] =
            (__bf16)accO[n][r];
      }
    }
  }
}

// ===========================================================================
// Fallback: round-1 fused kernel (used only if ws_size is too small).
// ===========================================================================
__launch_bounds__(256, 2)
__global__ void swin_attn_fused(const float* __restrict__ x,
                                const __bf16* __restrict__ wqkv_bf,
                                const float* __restrict__ bq_s,
                                const __bf16* __restrict__ wproj_bf,
                                const float* __restrict__ bproj,
                                float* __restrict__ out) {
  __shared__ __align__(16) __bf16 s_xw[49 * 512];
  __shared__ __align__(16) __bf16 s_q [49 * 64];
  __shared__ __align__(16) __bf16 s_k [49 * 64];
  __shared__ __align__(16) __bf16 s_vT[64 * 64];
  __shared__ __align__(16) __bf16 s_p [49 * 64];

  const int tid  = threadIdx.x;
  const int lane = tid & 63;
  const int wv   = tid >> 6;
  const int l15  = lane & 15;
  const int kg   = (lane >> 4) * 8;
  const int r4   = (lane >> 4) * 4;
  const int blk = blockIdx.x;
  const int b   = blk >> 10;
  const int wi  = blk & 1023;
  const int MOFF[4] = {0, 16, 32, 33};
  const float NEG_INF = -__builtin_inff();

  for (int i = tid; i < 64 * 64; i += 256) s_vT[i] = (__bf16)0.0f;
  const float* xwin = x + ((size_t)b * 50176 + (size_t)wi) * 512;
  for (int idx = tid; idx < 49 * 128; idx += 256) {
    const int row = idx >> 7;
    const int c4  = (idx & 127) * 4;
    const float4 v = *(const float4*)(xwin + (size_t)row * (1024 * 512) + c4);
    bf16x4 t;
    t.x = (__bf16)v.x; t.y = (__bf16)v.y; t.z = (__bf16)v.z; t.w = (__bf16)v.w;
    *(bf16x4*)&s_xw[row * 512 + swzi(row, c4)] = t;
  }
  f32x4 accF[4][8];
  const f32x4 zf = {0.f, 0.f, 0.f, 0.f};
#pragma unroll
  for (int m = 0; m < 4; ++m)
#pragma unroll
    for (int n = 0; n < 8; ++n) accF[m][n] = zf;
  __syncthreads();

  for (int h = 0; h < 8; ++h) {
    f32x4 accA[4][3];
#pragma unroll
    for (int m = 0; m < 4; ++m)
#pragma unroll
      for (int n = 0; n < 3; ++n) accA[m][n] = zf;
    const __bf16* pB[3];
    float biasv[3];
#pragma unroll
    for (int nt = 0; nt < 3; ++nt) {
      const int c  = wv * 48 + nt * 16 + l15;
      const int wr = (c < 64) ? (h * 64 + c)
                   : (c < 128) ? (512 + h * 64 + (c - 64))
                               : (1024 + h * 64 + (c - 128));
      pB[nt]    = wqkv_bf + (size_t)wr * 512 + kg;
      biasv[nt] = bq_s[wr];
    }
#pragma unroll
    for (int ks = 0; ks < 16; ++ks) {
      bf16x8 a[4], bb[3];
#pragma unroll
      for (int mt = 0; mt < 4; ++mt) {
        const int row = MOFF[mt] + l15;
        a[mt] = *(const bf16x8*)&s_xw[row * 512 + swzi(row, ks * 32 + kg)];
      }
#pragma unroll
      for (int nt = 0; nt < 3; ++nt) bb[nt] = *(const bf16x8*)(pB[nt] + ks * 32);
#pragma unroll
      for (int mt = 0; mt < 4; ++mt)
#pragma unroll
        for (int nt = 0; nt < 3; ++nt)
          accA[mt][nt] = MFMA_BF16(a[mt], bb[nt], accA[mt][nt]);
    }
#pragma unroll
    for (int nt = 0; nt < 3; ++nt) {
      const int c = wv * 48 + nt * 16 + l15;
#pragma unroll
      for (int mt = 0; mt < 4; ++mt) {
#pragma unroll
        for (int r = 0; r < 4; ++r) {
          const int row = MOFF[mt] + r4 + r;
          const __bf16 bvv = (__bf16)(accA[mt][nt][r] + biasv[nt]);
          if (c < 64)       s_q[row * 64 + swzi(row, c)] = bvv;
          else if (c < 128) s_k[row * 64 + swzi(row, c - 64)] = bvv;
          else {
            const int vr = c - 128;
            s_vT[vr * 64 + swzi(vr, row)] = bvv;
          }
        }
      }
    }
    __syncthreads();

    const int R = MOFF[wv];
    bf16x8 aq[2], bkf[4][2];
#pragma unroll
    for (int ks2 = 0; ks2 < 2; ++ks2) {
      const int row = R + l15;
      aq[ks2] = *(const bf16x8*)&s_q[row * 64 + swzi(row, ks2 * 32 + kg)];
    }
#pragma unroll
    for (int nt = 0; nt < 4; ++nt) {
      const int row = MOFF[nt] + l15;
#pragma unroll
      for (int ks2 = 0; ks2 < 2; ++ks2)
        bkf[nt][ks2] = *(const bf16x8*)&s_k[row * 64 + swzi(row, ks2 * 32 + kg)];
    }
    f32x4 accS[4];
#pragma unroll
    for (int n = 0; n < 4; ++n) accS[n] = zf;
#pragma unroll
    for (int ks2 = 0; ks2 < 2; ++ks2)
#pragma unroll
      for (int nt = 0; nt < 4; ++nt)
        accS[nt] = MFMA_BF16(aq[ks2], bkf[nt][ks2], accS[nt]);
#pragma unroll
    for (int r = 0; r < 4; ++r) {
      const int row = R + r4 + r;
      const float sv0 = accS[0][r];
      const float sv1 = accS[1][r];
      const float sv2 = accS[2][r];
      const float sv3 = (l15 == 15) ? accS[3][r] : NEG_INF;
      float m = fmaxf(fmaxf(sv0, sv1), fmaxf(sv2, sv3));
      m = fmaxf(m, __shfl_xor(m, 1));
      m = fmaxf(m, __shfl_xor(m, 2));
      m = fmaxf(m, __shfl_xor(m, 4));
      m = fmaxf(m, __shfl_xor(m, 8));
      const float e0 = __expf(sv0 - m);
      const float e1 = __expf(sv1 - m);
      const float e2 = __expf(sv2 - m);
      const float e3 = __expf(sv3 - m);
      float s = e0 + e1 + e2 + e3;
      s += __shfl_xor(s, 1);
      s += __shfl_xor(s, 2);
      s += __shfl_xor(s, 4);
      s += __shfl_xor(s, 8);
      const float inv = 1.0f / s;
      s_p[row * 64 + swzi(row, 0  + l15)] = (__bf16)(e0 * inv);
      s_p[row * 64 + swzi(row, 16 + l15)] = (__bf16)(e1 * inv);
      s_p[row * 64 + swzi(row, 32 + l15)] = (__bf16)(e2 * inv);
      if (l15 == 15) s_p[row * 64 + swzi(row, 48)] = (__bf16)(e3 * inv);
      if (l15 < 15)  s_p[row * 64 + swzi(row, 49 + l15)] = (__bf16)0.0f;
    }
    bf16x8 ap[2], bv2[4][2];
#pragma unroll
    for (int ks2 = 0; ks2 < 2; ++ks2) {
      const int row = R + l15;
      ap[ks2] = *(const bf16x8*)&s_p[row * 64 + swzi(row, ks2 * 32 + kg)];
    }
#pragma unroll
    for (int nt = 0; nt < 4; ++nt) {
      const int row = nt * 16 + l15;
#pragma unroll
      for (int ks2 = 0; ks2 < 2; ++ks2)
        bv2[nt][ks2] = *(const bf16x8*)&s_vT[row * 64 + swzi(row, ks2 * 32 + kg)];
    }
    __syncthreads();
    f32x4 accO[4];
#pragma unroll
    for (int n = 0; n < 4; ++n) accO[n] = zf;
#pragma unroll
    for (int ks2 = 0; ks2 < 2; ++ks2)
#pragma unroll
      for (int nt = 0; nt < 4; ++nt)
        accO[nt] = MFMA_BF16(ap[ks2], bv2[nt][ks2], accO[nt]);
#pragma unroll
    for (int nt = 0; nt < 4; ++nt) {
#pragma unroll
      for (int r = 0; r < 4; ++r) {
        const int row = R + r4 + r;
        s_p[row * 64 + swzi(row, nt * 16 + l15)] = (__bf16)accO[nt][r];
      }
    }
    __syncthreads();
#pragma unroll
    for (int ks2 = 0; ks2 < 2; ++ks2) {
      bf16x8 ao[4], bw[8];
#pragma unroll
      for (int mt = 0; mt < 4; ++mt) {
        const int row = MOFF[mt] + l15;
        ao[mt] = *(const bf16x8*)&s_p[row * 64 + swzi(row, ks2 * 32 + kg)];
      }
#pragma unroll
      for (int nt = 0; nt < 8; ++nt) {
        const int cc = wv * 128 + nt * 16 + l15;
        bw[nt] = *(const bf16x8*)(wproj_bf + (size_t)cc * 512 + h * 64 + ks2 * 32 + kg);
      }
#pragma unroll
      for (int mt = 0; mt < 4; ++mt)
#pragma unroll
        for (int nt = 0; nt < 8; ++nt)
          accF[mt][nt] = MFMA_BF16(ao[mt], bw[nt], accF[mt][nt]);
    }
  }
#pragma unroll
  for (int nt = 0; nt < 8; ++nt) {
    const int cc = wv * 128 + nt * 16 + l15;
    const float bp = bproj[cc];
#pragma unroll
    for (int mt = 0; mt < 4; ++mt) {
#pragma unroll
      for (int r = 0; r < 4; ++r) {
        const int row = MOFF[mt] + r4 + r;
        if (mt < 3 || (r4 + r) == 15) {
          out[((size_t)b * 50176 + (size_t)row * 1024 + (size_t)wi) * 512 + cc] =
              accF[mt][nt][r] + bp;
        }
      }
    }
  }
}

// ---------------------------------------------------------------------------
extern "C" void kernel_launch(void* const* d_in, const int* in_sizes, int n_in,
                              void* d_out, int out_size, void* d_ws, size_t ws_size,
                              hipStream_t stream) {
  const float* x      = (const float*)d_in[0];
  const float* w_qkv  = (const float*)d_in[1];
  const float* b_qkv  = (const float*)d_in[2];
  const float* w_proj = (const float*)d_in[3];
  const float* b_proj = (const float*)d_in[4];
  float* outp = (float*)d_out;

  // split-path workspace: qkv[200704*1536] O[200704*512] wqkv[786432]
  //                       wproj[262144] (all bf16) + bq_s[1536] f32
  const size_t QKV_E = (size_t)200704 * 1536;   // 308,281,344
  const size_t O_E   = (size_t)200704 * 512;    // 102,760,448
  const size_t NEED  = (QKV_E + O_E + 786432 + 262144) * 2 + 1536 * 4;

  if (ws_size >= NEED) {
    __bf16* qkv      = (__bf16*)d_ws;
    __bf16* Obuf     = qkv + QKV_E;
    __bf16* wqkv_bf  = Obuf + O_E;
    __bf16* wproj_bf = wqkv_bf + 786432;
    float*  bq_s     = (float*)(wproj_bf + 262144);

    prep_weights<<<1024, 256, 0, stream>>>(w_qkv, b_qkv, w_proj, wqkv_bf, wproj_bf, bq_s);
    gemm_bt<true,  false><<<1568 * 12, 256, 0, stream>>>(x,    wqkv_bf,  bq_s,   qkv,  1568, 12);
    attn_win<<<4096, 512, 0, stream>>>(qkv, Obuf);
    gemm_bt<false, true ><<<1568 * 4,  256, 0, stream>>>(Obuf, wproj_bf, b_proj, outp, 1568, 4);
  } else {
    __bf16* wqkv_bf  = (__bf16*)d_ws;
    __bf16* wproj_bf = wqkv_bf + 1536 * 512;
    float*  bq_s     = (float*)(wproj_bf + 512 * 512);
    prep_weights<<<1024, 256, 0, stream>>>(w_qkv, b_qkv, w_proj, wqkv_bf, wproj_bf, bq_s);
    swin_attn_fused<<<4096, 256, 0, stream>>>(x, wqkv_bf, bq_s, wproj_bf, b_proj, outp);
  }
}

// Round 3
// 1422.185 us; speedup vs baseline: 2.2715x; 1.1572x over previous
//
#include <hip/hip_runtime.h>
#include <cstdint>
#include <cstddef>

// ---------------------------------------------------------------------------
// ShuffleWindowAttention, MI355X (gfx950)
// B=4, N=50176, C=512, WS=49, w=1024 windows/batch, NH=8, hd=64
// Split pipeline: prep -> QKV GEMM -> windowed attention -> proj GEMM.
// R3: GEMM block order M-outer (A read once, B L2-resident) + LDS XOR swizzle
//     ((row>>1)&3)<<3 on 64B-row tiles -> 2-way (free) instead of 8-way.
// ---------------------------------------------------------------------------

typedef __bf16 bf16x8 __attribute__((ext_vector_type(8)));
typedef __bf16 bf16x4 __attribute__((ext_vector_type(4)));
typedef float  f32x4  __attribute__((ext_vector_type(4)));

#define MFMA_BF16(a, b, c) __builtin_amdgcn_mfma_f32_16x16x32_bf16((a), (b), (c), 0, 0, 0)

static __device__ __forceinline__ int swzi(int row, int col) {
  return col ^ ((row & 7) << 3);   // attn kernels' swizzle (128B rows)
}
// GEMM tiles: 32-elem (64B) rows, 8-elem (16B) accesses
static __device__ __forceinline__ int gswz(int row, int col) {
  return col ^ (((row >> 1) & 3) << 3);
}

typedef __attribute__((address_space(1))) const void gconst_t;
typedef __attribute__((address_space(3))) void lds_t;
static __device__ __forceinline__ void gload16(const void* g, void* l) {
  __builtin_amdgcn_global_load_lds((gconst_t*)g, (lds_t*)l, 16, 0, 0);
}

// ---------------------------------------------------------------------------
__global__ void prep_weights(const float* __restrict__ wqkv,
                             const float* __restrict__ bqkv,
                             const float* __restrict__ wproj,
                             __bf16* __restrict__ wqkv_bf,
                             __bf16* __restrict__ wproj_bf,
                             float* __restrict__ bq_s) {
  const int stride = gridDim.x * blockDim.x;
  const int t0 = blockIdx.x * blockDim.x + threadIdx.x;
  for (int i = t0; i < 1536 * 512; i += stride) {
    float v = wqkv[i];
    if (i < 512 * 512) v *= 0.125f;
    wqkv_bf[i] = (__bf16)v;
  }
  for (int i = t0; i < 512 * 512; i += stride) wproj_bf[i] = (__bf16)wproj[i];
  for (int i = t0; i < 1536; i += stride)      bq_s[i] = (i < 512 ? 0.125f : 1.0f) * bqkv[i];
}

// ---------------------------------------------------------------------------
// GEMM: C[M][N] = A[M][512] @ B[N][512]^T + bias.  128x128 tile, 4 waves,
// BK=32, double-buffered LDS.  M-outer block order; LDS XOR-swizzled.
// ---------------------------------------------------------------------------
template<bool A_F32, bool OUT_F32>
__launch_bounds__(256)
__global__ void gemm_bt(const void* __restrict__ Av,
                        const __bf16* __restrict__ Bw,   // [N][512]
                        const float* __restrict__ bias,  // [N]
                        void* __restrict__ Cv,
                        int Mtiles, int Ntiles) {
  __shared__ __align__(16) __bf16 sA[2][128 * 32];
  __shared__ __align__(16) __bf16 sB[2][128 * 32];

  const int tid  = threadIdx.x;
  const int lane = tid & 63;
  const int l15  = lane & 15;
  const int kg   = ((lane >> 4) & 3) * 8;
  const int r4   = ((lane >> 4) & 3) * 4;
  const int wv   = tid >> 6, wm = wv >> 1, wn = wv & 1;

  const int nwg = Mtiles * Ntiles;
  const int cpx = nwg >> 3;                       // nwg % 8 == 0 for our grids
  const int wg  = (blockIdx.x & 7) * cpx + (blockIdx.x >> 3);
  const int mt  = wg / Ntiles;                    // M-outer: A-tile reused
  const int nt  = wg % Ntiles;                    // across N-tiles in XCD L2
  const size_t m0 = (size_t)mt * 128;
  const int    n0 = nt * 128;

  const float*  Af = (const float*)Av;
  const __bf16* Ab = (const __bf16*)Av;

  // gload_lds: LDS slot (row = j*64 + tid>>2, col = (tid&3)*8), linear dest.
  // Source column pre-swizzled so LDS holds T[row][c] = B[row][c ^ gswz(row)].
  const int srow  = tid >> 2;
  const int scol8 = ((tid & 3) * 8) ^ (((tid >> 3) & 3) << 3);  // gswz(srow)
  // fp32-A reg-stage mapping: row = tid&127, seg = (tid>>7)*16
  const int arow = tid & 127;
  const int aseg = (tid >> 7) * 16;

  f32x4 acc[4][4];
  const f32x4 zf = {0.f, 0.f, 0.f, 0.f};
#pragma unroll
  for (int i = 0; i < 4; ++i)
#pragma unroll
    for (int j = 0; j < 4; ++j) acc[i][j] = zf;

  // ---- prologue: stage k-step 0 into buf 0 ----
  {
#pragma unroll
    for (int j = 0; j < 2; ++j)
      gload16(Bw + ((size_t)(n0 + j * 64 + srow)) * 512 + scol8,
              &sB[0][0] + (size_t)tid * 8 + j * 2048);
    if (A_F32) {
      float4 a4[4];
#pragma unroll
      for (int q = 0; q < 4; ++q)
        a4[q] = *(const float4*)(Af + (m0 + arow) * 512 + aseg + q * 4);
#pragma unroll
      for (int q = 0; q < 2; ++q) {
        bf16x8 t;
        t[0] = (__bf16)a4[q*2].x; t[1] = (__bf16)a4[q*2].y;
        t[2] = (__bf16)a4[q*2].z; t[3] = (__bf16)a4[q*2].w;
        t[4] = (__bf16)a4[q*2+1].x; t[5] = (__bf16)a4[q*2+1].y;
        t[6] = (__bf16)a4[q*2+1].z; t[7] = (__bf16)a4[q*2+1].w;
        *(bf16x8*)&sA[0][arow * 32 + gswz(arow, aseg + q * 8)] = t;
      }
    } else {
#pragma unroll
      for (int j = 0; j < 2; ++j)
        gload16(Ab + (m0 + j * 64 + srow) * 512 + scol8,
                &sA[0][0] + (size_t)tid * 8 + j * 2048);
    }
  }
  __syncthreads();

  int buf = 0;
  for (int kt = 0; kt < 16; ++kt) {
    const int k1 = (kt + 1) * 32;
    float4 a4[4];
    if (kt < 15) {
#pragma unroll
      for (int j = 0; j < 2; ++j)
        gload16(Bw + ((size_t)(n0 + j * 64 + srow)) * 512 + k1 + scol8,
                &sB[buf ^ 1][0] + (size_t)tid * 8 + j * 2048);
      if (A_F32) {
#pragma unroll
        for (int q = 0; q < 4; ++q)
          a4[q] = *(const float4*)(Af + (m0 + arow) * 512 + k1 + aseg + q * 4);
      } else {
#pragma unroll
        for (int j = 0; j < 2; ++j)
          gload16(Ab + (m0 + j * 64 + srow) * 512 + k1 + scol8,
                  &sA[buf ^ 1][0] + (size_t)tid * 8 + j * 2048);
      }
    }
    // compute current buffer (fragment reads un-swizzle with the same XOR)
    bf16x8 af[4], bfr[4];
#pragma unroll
    for (int m = 0; m < 4; ++m) {
      const int row = wm * 64 + m * 16 + l15;
      af[m] = *(const bf16x8*)&sA[buf][row * 32 + gswz(row, kg)];
    }
#pragma unroll
    for (int n = 0; n < 4; ++n) {
      const int row = wn * 64 + n * 16 + l15;
      bfr[n] = *(const bf16x8*)&sB[buf][row * 32 + gswz(row, kg)];
    }
#pragma unroll
    for (int m = 0; m < 4; ++m)
#pragma unroll
      for (int n = 0; n < 4; ++n)
        acc[m][n] = MFMA_BF16(af[m], bfr[n], acc[m][n]);

    if (A_F32 && kt < 15) {
#pragma unroll
      for (int q = 0; q < 2; ++q) {
        bf16x8 t;
        t[0] = (__bf16)a4[q*2].x; t[1] = (__bf16)a4[q*2].y;
        t[2] = (__bf16)a4[q*2].z; t[3] = (__bf16)a4[q*2].w;
        t[4] = (__bf16)a4[q*2+1].x; t[5] = (__bf16)a4[q*2+1].y;
        t[6] = (__bf16)a4[q*2+1].z; t[7] = (__bf16)a4[q*2+1].w;
        *(bf16x8*)&sA[buf ^ 1][arow * 32 + gswz(arow, aseg + q * 8)] = t;
      }
    }
    __syncthreads();
    buf ^= 1;
  }

  // ---- epilogue ----
  const int Nld = Ntiles * 128;
#pragma unroll
  for (int n = 0; n < 4; ++n) {
    const int col = n0 + wn * 64 + n * 16 + l15;
    const float bb = bias[col];
#pragma unroll
    for (int m = 0; m < 4; ++m) {
#pragma unroll
      for (int r = 0; r < 4; ++r) {
        const size_t row = m0 + wm * 64 + m * 16 + r4 + r;
        const float v = acc[m][n][r] + bb;
        if (OUT_F32) ((float*)Cv)[row * (size_t)Nld + col] = v;
        else         ((__bf16*)Cv)[row * (size_t)Nld + col] = (__bf16)v;
      }
    }
  }
}

// ---------------------------------------------------------------------------
// Windowed attention: one block (8 waves) per window, wave = head.
// qkv[token][1536] bf16 in;  O[token][512] bf16 out.
// ---------------------------------------------------------------------------
__launch_bounds__(512)
__global__ void attn_win(const __bf16* __restrict__ qkv, __bf16* __restrict__ O) {
  __shared__ __align__(16) __bf16 vT[8 * 64 * 64];   // [h][n][k ^ swz(n)]
  __shared__ __align__(16) __bf16 sP[8][16 * 64];    // per-wave P tile

  const int tid  = threadIdx.x;
  const int lane = tid & 63;
  const int h    = tid >> 6;                 // wave = head
  const int l15  = lane & 15;
  const int kg   = ((lane >> 4) & 3) * 8;
  const int r4   = ((lane >> 4) & 3) * 4;

  const int blk = blockIdx.x;
  const int b   = blk >> 10;
  const int wi  = blk & 1023;
  const size_t tokbase = (size_t)b * 50176 + wi;   // token(s) = tokbase + s*1024

  const int MOFF[4] = {0, 16, 32, 33};
  const float NEG_INF = -__builtin_inff();

  // ---- issue q,k fragment loads early (overlap with V staging) ----
  bf16x8 aq[4][2], bk[4][2];
#pragma unroll
  for (int mt = 0; mt < 4; ++mt) {
    const size_t tok = tokbase + (size_t)(MOFF[mt] + l15) * 1024;
#pragma unroll
    for (int ks = 0; ks < 2; ++ks) {
      aq[mt][ks] = *(const bf16x8*)(qkv + tok * 1536 +       h * 64 + ks * 32 + kg);
      bk[mt][ks] = *(const bf16x8*)(qkv + tok * 1536 + 512 + h * 64 + ks * 32 + kg);
    }
  }

  // ---- zero vT pad rows k = 49..63 ----
  for (int i = tid; i < 8 * 64 * 16; i += 512) {
    const int k = 48 + (i & 15);
    if (k != 48) {
      const int n  = (i >> 4) & 63;
      const int hh = i >> 10;
      vT[hh * 4096 + n * 64 + (k ^ ((n & 7) << 3))] = (__bf16)0.0f;
    }
  }
  // ---- stage V transposed (+swizzled) ----
  for (int i = tid; i < 49 * 64; i += 512) {
    const int s  = i >> 6;
    const int c8 = (i & 63) * 8;
    bf16x8 v8 = *(const bf16x8*)(qkv + (tokbase + (size_t)s * 1024) * 1536 + 1024 + c8);
    const int hh = c8 >> 6;
#pragma unroll
    for (int j = 0; j < 8; ++j) {
      const int n = (c8 & 63) + j;
      vT[hh * 4096 + n * 64 + (s ^ ((n & 7) << 3))] = v8[j];
    }
  }
  __syncthreads();

  // ---- V fragments (conflict-free via swizzle) ----
  bf16x8 bv[4][2];
#pragma unroll
  for (int ntv = 0; ntv < 4; ++ntv) {
    const int n = ntv * 16 + l15;
#pragma unroll
    for (int ks = 0; ks < 2; ++ks)
      bv[ntv][ks] = *(const bf16x8*)&vT[h * 4096 + n * 64 + ((ks * 32 + kg) ^ ((n & 7) << 3))];
  }

  // ---- S = q k^T ----
  f32x4 accS[4][4];
  const f32x4 zf = {0.f, 0.f, 0.f, 0.f};
#pragma unroll
  for (int m = 0; m < 4; ++m)
#pragma unroll
    for (int n = 0; n < 4; ++n) accS[m][n] = zf;
#pragma unroll
  for (int ks = 0; ks < 2; ++ks)
#pragma unroll
    for (int m = 0; m < 4; ++m)
#pragma unroll
      for (int n = 0; n < 4; ++n)
        accS[m][n] = MFMA_BF16(aq[m][ks], bk[n][ks], accS[m][n]);

  // ---- per row-tile: softmax -> P (LDS) -> PV -> store O ----
#pragma unroll
  for (int mt = 0; mt < 4; ++mt) {
#pragma unroll
    for (int r = 0; r < 4; ++r) {
      const int prow = r4 + r;
      const float sv0 = accS[mt][0][r];
      const float sv1 = accS[mt][1][r];
      const float sv2 = accS[mt][2][r];
      const float sv3 = (l15 == 15) ? accS[mt][3][r] : NEG_INF;
      float mx = fmaxf(fmaxf(sv0, sv1), fmaxf(sv2, sv3));
      mx = fmaxf(mx, __shfl_xor(mx, 1));
      mx = fmaxf(mx, __shfl_xor(mx, 2));
      mx = fmaxf(mx, __shfl_xor(mx, 4));
      mx = fmaxf(mx, __shfl_xor(mx, 8));
      const float e0 = __expf(sv0 - mx);
      const float e1 = __expf(sv1 - mx);
      const float e2 = __expf(sv2 - mx);
      const float e3 = __expf(sv3 - mx);      // 0 for masked lanes
      float sum = e0 + e1 + e2 + e3;
      sum += __shfl_xor(sum, 1);
      sum += __shfl_xor(sum, 2);
      sum += __shfl_xor(sum, 4);
      sum += __shfl_xor(sum, 8);
      const float inv = 1.0f / sum;
      sP[h][prow * 64 + swzi(prow, 0  + l15)] = (__bf16)(e0 * inv);
      sP[h][prow * 64 + swzi(prow, 16 + l15)] = (__bf16)(e1 * inv);
      sP[h][prow * 64 + swzi(prow, 32 + l15)] = (__bf16)(e2 * inv);
      if (l15 == 15) sP[h][prow * 64 + swzi(prow, 48)] = (__bf16)(e3 * inv);
      if (l15 < 15)  sP[h][prow * 64 + swzi(prow, 49 + l15)] = (__bf16)0.0f;
    }
    bf16x8 ap[2];
#pragma unroll
    for (int ks = 0; ks < 2; ++ks)
      ap[ks] = *(const bf16x8*)&sP[h][l15 * 64 + swzi(l15, ks * 32 + kg)];
    f32x4 accO[4];
#pragma unroll
    for (int n = 0; n < 4; ++n) accO[n] = zf;
#pragma unroll
    for (int ks = 0; ks < 2; ++ks)
#pragma unroll
      for (int n = 0; n < 4; ++n)
        accO[n] = MFMA_BF16(ap[ks], bv[n][ks], accO[n]);
#pragma unroll
    for (int n = 0; n < 4; ++n) {
#pragma unroll
      for (int r = 0; r < 4; ++r) {
        const int row = MOFF[mt] + r4 + r;
        O[(tokbase + (size_t)row * 1024) * 512 + h * 64 + n * 16 + l15] =
            (__bf16)accO[n][r];
      }
    }
  }
}

// ===========================================================================
// Fallback: round-1 fused kernel (used only if ws_size is too small).
// ===========================================================================
__launch_bounds__(256, 2)
__global__ void swin_attn_fused(const float* __restrict__ x,
                                const __bf16* __restrict__ wqkv_bf,
                                const float* __restrict__ bq_s,
                                const __bf16* __restrict__ wproj_bf,
                                const float* __restrict__ bproj,
                                float* __restrict__ out) {
  __shared__ __align__(16) __bf16 s_xw[49 * 512];
  __shared__ __align__(16) __bf16 s_q [49 * 64];
  __shared__ __align__(16) __bf16 s_k [49 * 64];
  __shared__ __align__(16) __bf16 s_vT[64 * 64];
  __shared__ __align__(16) __bf16 s_p [49 * 64];

  const int tid  = threadIdx.x;
  const int lane = tid & 63;
  const int wv   = tid >> 6;
  const int l15  = lane & 15;
  const int kg   = (lane >> 4) * 8;
  const int r4   = (lane >> 4) * 4;
  const int blk = blockIdx.x;
  const int b   = blk >> 10;
  const int wi  = blk & 1023;
  const int MOFF[4] = {0, 16, 32, 33};
  const float NEG_INF = -__builtin_inff();

  for (int i = tid; i < 64 * 64; i += 256) s_vT[i] = (__bf16)0.0f;
  const float* xwin = x + ((size_t)b * 50176 + (size_t)wi) * 512;
  for (int idx = tid; idx < 49 * 128; idx += 256) {
    const int row = idx >> 7;
    const int c4  = (idx & 127) * 4;
    const float4 v = *(const float4*)(xwin + (size_t)row * (1024 * 512) + c4);
    bf16x4 t;
    t.x = (__bf16)v.x; t.y = (__bf16)v.y; t.z = (__bf16)v.z; t.w = (__bf16)v.w;
    *(bf16x4*)&s_xw[row * 512 + swzi(row, c4)] = t;
  }
  f32x4 accF[4][8];
  const f32x4 zf = {0.f, 0.f, 0.f, 0.f};
#pragma unroll
  for (int m = 0; m < 4; ++m)
#pragma unroll
    for (int n = 0; n < 8; ++n) accF[m][n] = zf;
  __syncthreads();

  for (int h = 0; h < 8; ++h) {
    f32x4 accA[4][3];
#pragma unroll
    for (int m = 0; m < 4; ++m)
#pragma unroll
      for (int n = 0; n < 3; ++n) accA[m][n] = zf;
    const __bf16* pB[3];
    float biasv[3];
#pragma unroll
    for (int nt = 0; nt < 3; ++nt) {
      const int c  = wv * 48 + nt * 16 + l15;
      const int wr = (c < 64) ? (h * 64 + c)
                   : (c < 128) ? (512 + h * 64 + (c - 64))
                               : (1024 + h * 64 + (c - 128));
      pB[nt]    = wqkv_bf + (size_t)wr * 512 + kg;
      biasv[nt] = bq_s[wr];
    }
#pragma unroll
    for (int ks = 0; ks < 16; ++ks) {
      bf16x8 a[4], bb[3];
#pragma unroll
      for (int mt = 0; mt < 4; ++mt) {
        const int row = MOFF[mt] + l15;
        a[mt] = *(const bf16x8*)&s_xw[row * 512 + swzi(row, ks * 32 + kg)];
      }
#pragma unroll
      for (int nt = 0; nt < 3; ++nt) bb[nt] = *(const bf16x8*)(pB[nt] + ks * 32);
#pragma unroll
      for (int mt = 0; mt < 4; ++mt)
#pragma unroll
        for (int nt = 0; nt < 3; ++nt)
          accA[mt][nt] = MFMA_BF16(a[mt], bb[nt], accA[mt][nt]);
    }
#pragma unroll
    for (int nt = 0; nt < 3; ++nt) {
      const int c = wv * 48 + nt * 16 + l15;
#pragma unroll
      for (int mt = 0; mt < 4; ++mt) {
#pragma unroll
        for (int r = 0; r < 4; ++r) {
          const int row = MOFF[mt] + r4 + r;
          const __bf16 bvv = (__bf16)(accA[mt][nt][r] + biasv[nt]);
          if (c < 64)       s_q[row * 64 + swzi(row, c)] = bvv;
          else if (c < 128) s_k[row * 64 + swzi(row, c - 64)] = bvv;
          else {
            const int vr = c - 128;
            s_vT[vr * 64 + swzi(vr, row)] = bvv;
          }
        }
      }
    }
    __syncthreads();

    const int R = MOFF[wv];
    bf16x8 aq[2], bkf[4][2];
#pragma unroll
    for (int ks2 = 0; ks2 < 2; ++ks2) {
      const int row = R + l15;
      aq[ks2] = *(const bf16x8*)&s_q[row * 64 + swzi(row, ks2 * 32 + kg)];
    }
#pragma unroll
    for (int nt = 0; nt < 4; ++nt) {
      const int row = MOFF[nt] + l15;
#pragma unroll
      for (int ks2 = 0; ks2 < 2; ++ks2)
        bkf[nt][ks2] = *(const bf16x8*)&s_k[row * 64 + swzi(row, ks2 * 32 + kg)];
    }
    f32x4 accS[4];
#pragma unroll
    for (int n = 0; n < 4; ++n) accS[n] = zf;
#pragma unroll
    for (int ks2 = 0; ks2 < 2; ++ks2)
#pragma unroll
      for (int nt = 0; nt < 4; ++nt)
        accS[nt] = MFMA_BF16(aq[ks2], bkf[nt][ks2], accS[nt]);
#pragma unroll
    for (int r = 0; r < 4; ++r) {
      const int row = R + r4 + r;
      const float sv0 = accS[0][r];
      const float sv1 = accS[1][r];
      const float sv2 = accS[2][r];
      const float sv3 = (l15 == 15) ? accS[3][r] : NEG_INF;
      float m = fmaxf(fmaxf(sv0, sv1), fmaxf(sv2, sv3));
      m = fmaxf(m, __shfl_xor(m, 1));
      m = fmaxf(m, __shfl_xor(m, 2));
      m = fmaxf(m, __shfl_xor(m, 4));
      m = fmaxf(m, __shfl_xor(m, 8));
      const float e0 = __expf(sv0 - m);
      const float e1 = __expf(sv1 - m);
      const float e2 = __expf(sv2 - m);
      const float e3 = __expf(sv3 - m);
      float s = e0 + e1 + e2 + e3;
      s += __shfl_xor(s, 1);
      s += __shfl_xor(s, 2);
      s += __shfl_xor(s, 4);
      s += __shfl_xor(s, 8);
      const float inv = 1.0f / s;
      s_p[row * 64 + swzi(row, 0  + l15)] = (__bf16)(e0 * inv);
      s_p[row * 64 + swzi(row, 16 + l15)] = (__bf16)(e1 * inv);
      s_p[row * 64 + swzi(row, 32 + l15)] = (__bf16)(e2 * inv);
      if (l15 == 15) s_p[row * 64 + swzi(row, 48)] = (__bf16)(e3 * inv);
      if (l15 < 15)  s_p[row * 64 + swzi(row, 49 + l15)] = (__bf16)0.0f;
    }
    bf16x8 ap[2], bv2[4][2];
#pragma unroll
    for (int ks2 = 0; ks2 < 2; ++ks2) {
      const int row = R + l15;
      ap[ks2] = *(const bf16x8*)&s_p[row * 64 + swzi(row, ks2 * 32 + kg)];
    }
#pragma unroll
    for (int nt = 0; nt < 4; ++nt) {
      const int row = nt * 16 + l15;
#pragma unroll
      for (int ks2 = 0; ks2 < 2; ++ks2)
        bv2[nt][ks2] = *(const bf16x8*)&s_vT[row * 64 + swzi(row, ks2 * 32 + kg)];
    }
    __syncthreads();
    f32x4 accO[4];
#pragma unroll
    for (int n = 0; n < 4; ++n) accO[n] = zf;
#pragma unroll
    for (int ks2 = 0; ks2 < 2; ++ks2)
#pragma unroll
      for (int nt = 0; nt < 4; ++nt)
        accO[nt] = MFMA_BF16(ap[ks2], bv2[nt][ks2], accO[nt]);
#pragma unroll
    for (int nt = 0; nt < 4; ++nt) {
#pragma unroll
      for (int r = 0; r < 4; ++r) {
        const int row = R + r4 + r;
        s_p[row * 64 + swzi(row, nt * 16 + l15)] = (__bf16)accO[nt][r];
      }
    }
    __syncthreads();
#pragma unroll
    for (int ks2 = 0; ks2 < 2; ++ks2) {
      bf16x8 ao[4], bw[8];
#pragma unroll
      for (int mt = 0; mt < 4; ++mt) {
        const int row = MOFF[mt] + l15;
        ao[mt] = *(const bf16x8*)&s_p[row * 64 + swzi(row, ks2 * 32 + kg)];
      }
#pragma unroll
      for (int nt = 0; nt < 8; ++nt) {
        const int cc = wv * 128 + nt * 16 + l15;
        bw[nt] = *(const bf16x8*)(wproj_bf + (size_t)cc * 512 + h * 64 + ks2 * 32 + kg);
      }
#pragma unroll
      for (int mt = 0; mt < 4; ++mt)
#pragma unroll
        for (int nt = 0; nt < 8; ++nt)
          accF[mt][nt] = MFMA_BF16(ao[mt], bw[nt], accF[mt][nt]);
    }
  }
#pragma unroll
  for (int nt = 0; nt < 8; ++nt) {
    const int cc = wv * 128 + nt * 16 + l15;
    const float bp = bproj[cc];
#pragma unroll
    for (int mt = 0; mt < 4; ++mt) {
#pragma unroll
      for (int r = 0; r < 4; ++r) {
        const int row = MOFF[mt] + r4 + r;
        if (mt < 3 || (r4 + r) == 15) {
          out[((size_t)b * 50176 + (size_t)row * 1024 + (size_t)wi) * 512 + cc] =
              accF[mt][nt][r] + bp;
        }
      }
    }
  }
}

// ---------------------------------------------------------------------------
extern "C" void kernel_launch(void* const* d_in, const int* in_sizes, int n_in,
                              void* d_out, int out_size, void* d_ws, size_t ws_size,
                              hipStream_t stream) {
  const float* x      = (const float*)d_in[0];
  const float* w_qkv  = (const float*)d_in[1];
  const float* b_qkv  = (const float*)d_in[2];
  const float* w_proj = (const float*)d_in[3];
  const float* b_proj = (const float*)d_in[4];
  float* outp = (float*)d_out;

  const size_t QKV_E = (size_t)200704 * 1536;
  const size_t O_E   = (size_t)200704 * 512;
  const size_t NEED  = (QKV_E + O_E + 786432 + 262144) * 2 + 1536 * 4;

  if (ws_size >= NEED) {
    __bf16* qkv      = (__bf16*)d_ws;
    __bf16* Obuf     = qkv + QKV_E;
    __bf16* wqkv_bf  = Obuf + O_E;
    __bf16* wproj_bf = wqkv_bf + 786432;
    float*  bq_s     = (float*)(wproj_bf + 262144);

    prep_weights<<<1024, 256, 0, stream>>>(w_qkv, b_qkv, w_proj, wqkv_bf, wproj_bf, bq_s);
    gemm_bt<true,  false><<<1568 * 12, 256, 0, stream>>>(x,    wqkv_bf,  bq_s,   qkv,  1568, 12);
    attn_win<<<4096, 512, 0, stream>>>(qkv, Obuf);
    gemm_bt<false, true ><<<1568 * 4,  256, 0, stream>>>(Obuf, wproj_bf, b_proj, outp, 1568, 4);
  } else {
    __bf16* wqkv_bf  = (__bf16*)d_ws;
    __bf16* wproj_bf = wqkv_bf + 1536 * 512;
    float*  bq_s     = (float*)(wproj_bf + 512 * 512);
    prep_weights<<<1024, 256, 0, stream>>>(w_qkv, b_qkv, w_proj, wqkv_bf, wproj_bf, bq_s);
    swin_attn_fused<<<4096, 256, 0, stream>>>(x, wqkv_bf, bq_s, wproj_bf, b_proj, outp);
  }
}

// Round 4
// 1156.025 us; speedup vs baseline: 2.7944x; 1.2302x over previous
//
#include <hip/hip_runtime.h>
#include <cstdint>
#include <cstddef>

// ---------------------------------------------------------------------------
// ShuffleWindowAttention, MI355X (gfx950)
// B=4, N=50176, C=512, WS=49, w=1024 windows/batch, NH=8, hd=64
// Pipeline: prep_weights + prep_x (fp32->bf16) -> QKV GEMM (pure bf16,
// global_load_lds both operands) -> windowed attention -> proj GEMM.
// x_bf16 lives in the O buffer slot (dead by the time attn overwrites it).
// ---------------------------------------------------------------------------

typedef __bf16 bf16x8 __attribute__((ext_vector_type(8)));
typedef __bf16 bf16x4 __attribute__((ext_vector_type(4)));
typedef float  f32x4  __attribute__((ext_vector_type(4)));

#define MFMA_BF16(a, b, c) __builtin_amdgcn_mfma_f32_16x16x32_bf16((a), (b), (c), 0, 0, 0)

static __device__ __forceinline__ int swzi(int row, int col) {
  return col ^ ((row & 7) << 3);   // attn kernels' swizzle (128B rows)
}
// GEMM tiles: 32-elem (64B) rows, 8-elem (16B) accesses
static __device__ __forceinline__ int gswz(int row, int col) {
  return col ^ (((row >> 1) & 3) << 3);
}

typedef __attribute__((address_space(1))) const void gconst_t;
typedef __attribute__((address_space(3))) void lds_t;
static __device__ __forceinline__ void gload16(const void* g, void* l) {
  __builtin_amdgcn_global_load_lds((gconst_t*)g, (lds_t*)l, 16, 0, 0);
}

// ---------------------------------------------------------------------------
__global__ void prep_weights(const float* __restrict__ wqkv,
                             const float* __restrict__ bqkv,
                             const float* __restrict__ wproj,
                             __bf16* __restrict__ wqkv_bf,
                             __bf16* __restrict__ wproj_bf,
                             float* __restrict__ bq_s) {
  const int stride = gridDim.x * blockDim.x;
  const int t0 = blockIdx.x * blockDim.x + threadIdx.x;
  for (int i = t0; i < 1536 * 512; i += stride) {
    float v = wqkv[i];
    if (i < 512 * 512) v *= 0.125f;
    wqkv_bf[i] = (__bf16)v;
  }
  for (int i = t0; i < 512 * 512; i += stride) wproj_bf[i] = (__bf16)wproj[i];
  for (int i = t0; i < 1536; i += stride)      bq_s[i] = (i < 512 ? 0.125f : 1.0f) * bqkv[i];
}

// x: fp32 [200704*512] -> bf16 (bandwidth-bound, 8 elems/thread/iter)
__global__ void prep_x(const float* __restrict__ x, __bf16* __restrict__ xb) {
  const size_t total  = (size_t)200704 * 512 / 8;
  const size_t stride = (size_t)gridDim.x * blockDim.x;
  for (size_t i = (size_t)blockIdx.x * blockDim.x + threadIdx.x; i < total; i += stride) {
    const float4 a = *(const float4*)(x + i * 8);
    const float4 b = *(const float4*)(x + i * 8 + 4);
    bf16x8 t;
    t[0] = (__bf16)a.x; t[1] = (__bf16)a.y; t[2] = (__bf16)a.z; t[3] = (__bf16)a.w;
    t[4] = (__bf16)b.x; t[5] = (__bf16)b.y; t[6] = (__bf16)b.z; t[7] = (__bf16)b.w;
    *(bf16x8*)(xb + i * 8) = t;
  }
}

// ---------------------------------------------------------------------------
// GEMM: C[M][N] = A[M][512] @ B[N][512]^T + bias.  128x128 tile, 4 waves,
// BK=32, double-buffered LDS, both operands via global_load_lds (bf16).
// M-outer block order (A-tile L2 reuse), XCD swizzle, pre-swizzled source col.
// ---------------------------------------------------------------------------
template<bool OUT_F32>
__launch_bounds__(256)
__global__ void gemm_bt(const __bf16* __restrict__ Ab,   // [M][512]
                        const __bf16* __restrict__ Bw,   // [N][512]
                        const float* __restrict__ bias,  // [N]
                        void* __restrict__ Cv,
                        int Mtiles, int Ntiles) {
  __shared__ __align__(16) __bf16 sA[2][128 * 32];
  __shared__ __align__(16) __bf16 sB[2][128 * 32];

  const int tid  = threadIdx.x;
  const int lane = tid & 63;
  const int l15  = lane & 15;
  const int kg   = ((lane >> 4) & 3) * 8;
  const int r4   = ((lane >> 4) & 3) * 4;
  const int wv   = tid >> 6, wm = wv >> 1, wn = wv & 1;

  const int nwg = Mtiles * Ntiles;
  const int cpx = nwg >> 3;                       // nwg % 8 == 0 for our grids
  const int wg  = (blockIdx.x & 7) * cpx + (blockIdx.x >> 3);
  const int mt  = wg / Ntiles;                    // M-outer: A-tile reused
  const int nt  = wg % Ntiles;
  const size_t m0 = (size_t)mt * 128;
  const int    n0 = nt * 128;

  // gload_lds: LDS slot (row = j*64 + tid>>2, col = (tid&3)*8), linear dest.
  // Source column pre-swizzled so LDS holds T[row][c] = src[row][c ^ gswz(row)].
  const int srow  = tid >> 2;
  const int scol8 = ((tid & 3) * 8) ^ (((tid >> 3) & 3) << 3);  // gswz(srow)

  f32x4 acc[4][4];
  const f32x4 zf = {0.f, 0.f, 0.f, 0.f};
#pragma unroll
  for (int i = 0; i < 4; ++i)
#pragma unroll
    for (int j = 0; j < 4; ++j) acc[i][j] = zf;

  // ---- prologue: stage k-step 0 into buf 0 ----
#pragma unroll
  for (int j = 0; j < 2; ++j) {
    gload16(Bw + ((size_t)(n0 + j * 64 + srow)) * 512 + scol8,
            &sB[0][0] + (size_t)tid * 8 + j * 2048);
    gload16(Ab + (m0 + j * 64 + srow) * 512 + scol8,
            &sA[0][0] + (size_t)tid * 8 + j * 2048);
  }
  __syncthreads();

  int buf = 0;
  for (int kt = 0; kt < 16; ++kt) {
    const int k1 = (kt + 1) * 32;
    if (kt < 15) {
#pragma unroll
      for (int j = 0; j < 2; ++j) {
        gload16(Bw + ((size_t)(n0 + j * 64 + srow)) * 512 + k1 + scol8,
                &sB[buf ^ 1][0] + (size_t)tid * 8 + j * 2048);
        gload16(Ab + (m0 + j * 64 + srow) * 512 + k1 + scol8,
                &sA[buf ^ 1][0] + (size_t)tid * 8 + j * 2048);
      }
    }
    // compute current buffer (fragment reads un-swizzle with the same XOR)
    bf16x8 af[4], bfr[4];
#pragma unroll
    for (int m = 0; m < 4; ++m) {
      const int row = wm * 64 + m * 16 + l15;
      af[m] = *(const bf16x8*)&sA[buf][row * 32 + gswz(row, kg)];
    }
#pragma unroll
    for (int n = 0; n < 4; ++n) {
      const int row = wn * 64 + n * 16 + l15;
      bfr[n] = *(const bf16x8*)&sB[buf][row * 32 + gswz(row, kg)];
    }
#pragma unroll
    for (int m = 0; m < 4; ++m)
#pragma unroll
      for (int n = 0; n < 4; ++n)
        acc[m][n] = MFMA_BF16(af[m], bfr[n], acc[m][n]);

    __syncthreads();
    buf ^= 1;
  }

  // ---- epilogue ----
  const int Nld = Ntiles * 128;
#pragma unroll
  for (int n = 0; n < 4; ++n) {
    const int col = n0 + wn * 64 + n * 16 + l15;
    const float bb = bias[col];
#pragma unroll
    for (int m = 0; m < 4; ++m) {
#pragma unroll
      for (int r = 0; r < 4; ++r) {
        const size_t row = m0 + wm * 64 + m * 16 + r4 + r;
        const float v = acc[m][n][r] + bb;
        if (OUT_F32) ((float*)Cv)[row * (size_t)Nld + col] = v;
        else         ((__bf16*)Cv)[row * (size_t)Nld + col] = (__bf16)v;
      }
    }
  }
}

// ---------------------------------------------------------------------------
// Windowed attention: one block (8 waves) per window, wave = head.
// qkv[token][1536] bf16 in;  O[token][512] bf16 out.
// ---------------------------------------------------------------------------
__launch_bounds__(512)
__global__ void attn_win(const __bf16* __restrict__ qkv, __bf16* __restrict__ O) {
  __shared__ __align__(16) __bf16 vT[8 * 64 * 64];   // [h][n][k ^ swz(n)]
  __shared__ __align__(16) __bf16 sP[8][16 * 64];    // per-wave P tile

  const int tid  = threadIdx.x;
  const int lane = tid & 63;
  const int h    = tid >> 6;                 // wave = head
  const int l15  = lane & 15;
  const int kg   = ((lane >> 4) & 3) * 8;
  const int r4   = ((lane >> 4) & 3) * 4;

  const int blk = blockIdx.x;
  const int b   = blk >> 10;
  const int wi  = blk & 1023;
  const size_t tokbase = (size_t)b * 50176 + wi;   // token(s) = tokbase + s*1024

  const int MOFF[4] = {0, 16, 32, 33};
  const float NEG_INF = -__builtin_inff();

  // ---- issue q,k fragment loads early (overlap with V staging) ----
  bf16x8 aq[4][2], bk[4][2];
#pragma unroll
  for (int mt = 0; mt < 4; ++mt) {
    const size_t tok = tokbase + (size_t)(MOFF[mt] + l15) * 1024;
#pragma unroll
    for (int ks = 0; ks < 2; ++ks) {
      aq[mt][ks] = *(const bf16x8*)(qkv + tok * 1536 +       h * 64 + ks * 32 + kg);
      bk[mt][ks] = *(const bf16x8*)(qkv + tok * 1536 + 512 + h * 64 + ks * 32 + kg);
    }
  }

  // ---- zero vT pad rows k = 49..63 ----
  for (int i = tid; i < 8 * 64 * 16; i += 512) {
    const int k = 48 + (i & 15);
    if (k != 48) {
      const int n  = (i >> 4) & 63;
      const int hh = i >> 10;
      vT[hh * 4096 + n * 64 + (k ^ ((n & 7) << 3))] = (__bf16)0.0f;
    }
  }
  // ---- stage V transposed (+swizzled) ----
  for (int i = tid; i < 49 * 64; i += 512) {
    const int s  = i >> 6;
    const int c8 = (i & 63) * 8;
    bf16x8 v8 = *(const bf16x8*)(qkv + (tokbase + (size_t)s * 1024) * 1536 + 1024 + c8);
    const int hh = c8 >> 6;
#pragma unroll
    for (int j = 0; j < 8; ++j) {
      const int n = (c8 & 63) + j;
      vT[hh * 4096 + n * 64 + (s ^ ((n & 7) << 3))] = v8[j];
    }
  }
  __syncthreads();

  // ---- V fragments (conflict-free via swizzle) ----
  bf16x8 bv[4][2];
#pragma unroll
  for (int ntv = 0; ntv < 4; ++ntv) {
    const int n = ntv * 16 + l15;
#pragma unroll
    for (int ks = 0; ks < 2; ++ks)
      bv[ntv][ks] = *(const bf16x8*)&vT[h * 4096 + n * 64 + ((ks * 32 + kg) ^ ((n & 7) << 3))];
  }

  // ---- S = q k^T ----
  f32x4 accS[4][4];
  const f32x4 zf = {0.f, 0.f, 0.f, 0.f};
#pragma unroll
  for (int m = 0; m < 4; ++m)
#pragma unroll
    for (int n = 0; n < 4; ++n) accS[m][n] = zf;
#pragma unroll
  for (int ks = 0; ks < 2; ++ks)
#pragma unroll
    for (int m = 0; m < 4; ++m)
#pragma unroll
      for (int n = 0; n < 4; ++n)
        accS[m][n] = MFMA_BF16(aq[m][ks], bk[n][ks], accS[m][n]);

  // ---- per row-tile: softmax -> P (LDS) -> PV -> store O ----
#pragma unroll
  for (int mt = 0; mt < 4; ++mt) {
#pragma unroll
    for (int r = 0; r < 4; ++r) {
      const int prow = r4 + r;
      const float sv0 = accS[mt][0][r];
      const float sv1 = accS[mt][1][r];
      const float sv2 = accS[mt][2][r];
      const float sv3 = (l15 == 15) ? accS[mt][3][r] : NEG_INF;
      float mx = fmaxf(fmaxf(sv0, sv1), fmaxf(sv2, sv3));
      mx = fmaxf(mx, __shfl_xor(mx, 1));
      mx = fmaxf(mx, __shfl_xor(mx, 2));
      mx = fmaxf(mx, __shfl_xor(mx, 4));
      mx = fmaxf(mx, __shfl_xor(mx, 8));
      const float e0 = __expf(sv0 - mx);
      const float e1 = __expf(sv1 - mx);
      const float e2 = __expf(sv2 - mx);
      const float e3 = __expf(sv3 - mx);      // 0 for masked lanes
      float sum = e0 + e1 + e2 + e3;
      sum += __shfl_xor(sum, 1);
      sum += __shfl_xor(sum, 2);
      sum += __shfl_xor(sum, 4);
      sum += __shfl_xor(sum, 8);
      const float inv = 1.0f / sum;
      sP[h][prow * 64 + swzi(prow, 0  + l15)] = (__bf16)(e0 * inv);
      sP[h][prow * 64 + swzi(prow, 16 + l15)] = (__bf16)(e1 * inv);
      sP[h][prow * 64 + swzi(prow, 32 + l15)] = (__bf16)(e2 * inv);
      if (l15 == 15) sP[h][prow * 64 + swzi(prow, 48)] = (__bf16)(e3 * inv);
      if (l15 < 15)  sP[h][prow * 64 + swzi(prow, 49 + l15)] = (__bf16)0.0f;
    }
    bf16x8 ap[2];
#pragma unroll
    for (int ks = 0; ks < 2; ++ks)
      ap[ks] = *(const bf16x8*)&sP[h][l15 * 64 + swzi(l15, ks * 32 + kg)];
    f32x4 accO[4];
#pragma unroll
    for (int n = 0; n < 4; ++n) accO[n] = zf;
#pragma unroll
    for (int ks = 0; ks < 2; ++ks)
#pragma unroll
      for (int n = 0; n < 4; ++n)
        accO[n] = MFMA_BF16(ap[ks], bv[n][ks], accO[n]);
#pragma unroll
    for (int n = 0; n < 4; ++n) {
#pragma unroll
      for (int r = 0; r < 4; ++r) {
        const int row = MOFF[mt] + r4 + r;
        O[(tokbase + (size_t)row * 1024) * 512 + h * 64 + n * 16 + l15] =
            (__bf16)accO[n][r];
      }
    }
  }
}

// ===========================================================================
// Fallback: round-1 fused kernel (used only if ws_size is too small).
// ===========================================================================
__launch_bounds__(256, 2)
__global__ void swin_attn_fused(const float* __restrict__ x,
                                const __bf16* __restrict__ wqkv_bf,
                                const float* __restrict__ bq_s,
                                const __bf16* __restrict__ wproj_bf,
                                const float* __restrict__ bproj,
                                float* __restrict__ out) {
  __shared__ __align__(16) __bf16 s_xw[49 * 512];
  __shared__ __align__(16) __bf16 s_q [49 * 64];
  __shared__ __align__(16) __bf16 s_k [49 * 64];
  __shared__ __align__(16) __bf16 s_vT[64 * 64];
  __shared__ __align__(16) __bf16 s_p [49 * 64];

  const int tid  = threadIdx.x;
  const int lane = tid & 63;
  const int wv   = tid >> 6;
  const int l15  = lane & 15;
  const int kg   = (lane >> 4) * 8;
  const int r4   = (lane >> 4) * 4;
  const int blk = blockIdx.x;
  const int b   = blk >> 10;
  const int wi  = blk & 1023;
  const int MOFF[4] = {0, 16, 32, 33};
  const float NEG_INF = -__builtin_inff();

  for (int i = tid; i < 64 * 64; i += 256) s_vT[i] = (__bf16)0.0f;
  const float* xwin = x + ((size_t)b * 50176 + (size_t)wi) * 512;
  for (int idx = tid; idx < 49 * 128; idx += 256) {
    const int row = idx >> 7;
    const int c4  = (idx & 127) * 4;
    const float4 v = *(const float4*)(xwin + (size_t)row * (1024 * 512) + c4);
    bf16x4 t;
    t.x = (__bf16)v.x; t.y = (__bf16)v.y; t.z = (__bf16)v.z; t.w = (__bf16)v.w;
    *(bf16x4*)&s_xw[row * 512 + swzi(row, c4)] = t;
  }
  f32x4 accF[4][8];
  const f32x4 zf = {0.f, 0.f, 0.f, 0.f};
#pragma unroll
  for (int m = 0; m < 4; ++m)
#pragma unroll
    for (int n = 0; n < 8; ++n) accF[m][n] = zf;
  __syncthreads();

  for (int h = 0; h < 8; ++h) {
    f32x4 accA[4][3];
#pragma unroll
    for (int m = 0; m < 4; ++m)
#pragma unroll
      for (int n = 0; n < 3; ++n) accA[m][n] = zf;
    const __bf16* pB[3];
    float biasv[3];
#pragma unroll
    for (int nt = 0; nt < 3; ++nt) {
      const int c  = wv * 48 + nt * 16 + l15;
      const int wr = (c < 64) ? (h * 64 + c)
                   : (c < 128) ? (512 + h * 64 + (c - 64))
                               : (1024 + h * 64 + (c - 128));
      pB[nt]    = wqkv_bf + (size_t)wr * 512 + kg;
      biasv[nt] = bq_s[wr];
    }
#pragma unroll
    for (int ks = 0; ks < 16; ++ks) {
      bf16x8 a[4], bb[3];
#pragma unroll
      for (int mt = 0; mt < 4; ++mt) {
        const int row = MOFF[mt] + l15;
        a[mt] = *(const bf16x8*)&s_xw[row * 512 + swzi(row, ks * 32 + kg)];
      }
#pragma unroll
      for (int nt = 0; nt < 3; ++nt) bb[nt] = *(const bf16x8*)(pB[nt] + ks * 32);
#pragma unroll
      for (int mt = 0; mt < 4; ++mt)
#pragma unroll
        for (int nt = 0; nt < 3; ++nt)
          accA[mt][nt] = MFMA_BF16(a[mt], bb[nt], accA[mt][nt]);
    }
#pragma unroll
    for (int nt = 0; nt < 3; ++nt) {
      const int c = wv * 48 + nt * 16 + l15;
#pragma unroll
      for (int mt = 0; mt < 4; ++mt) {
#pragma unroll
        for (int r = 0; r < 4; ++r) {
          const int row = MOFF[mt] + r4 + r;
          const __bf16 bvv = (__bf16)(accA[mt][nt][r] + biasv[nt]);
          if (c < 64)       s_q[row * 64 + swzi(row, c)] = bvv;
          else if (c < 128) s_k[row * 64 + swzi(row, c - 64)] = bvv;
          else {
            const int vr = c - 128;
            s_vT[vr * 64 + swzi(vr, row)] = bvv;
          }
        }
      }
    }
    __syncthreads();

    const int R = MOFF[wv];
    bf16x8 aq[2], bkf[4][2];
#pragma unroll
    for (int ks2 = 0; ks2 < 2; ++ks2) {
      const int row = R + l15;
      aq[ks2] = *(const bf16x8*)&s_q[row * 64 + swzi(row, ks2 * 32 + kg)];
    }
#pragma unroll
    for (int nt = 0; nt < 4; ++nt) {
      const int row = MOFF[nt] + l15;
#pragma unroll
      for (int ks2 = 0; ks2 < 2; ++ks2)
        bkf[nt][ks2] = *(const bf16x8*)&s_k[row * 64 + swzi(row, ks2 * 32 + kg)];
    }
    f32x4 accS[4];
#pragma unroll
    for (int n = 0; n < 4; ++n) accS[n] = zf;
#pragma unroll
    for (int ks2 = 0; ks2 < 2; ++ks2)
#pragma unroll
      for (int nt = 0; nt < 4; ++nt)
        accS[nt] = MFMA_BF16(aq[ks2], bkf[nt][ks2], accS[nt]);
#pragma unroll
    for (int r = 0; r < 4; ++r) {
      const int row = R + r4 + r;
      const float sv0 = accS[0][r];
      const float sv1 = accS[1][r];
      const float sv2 = accS[2][r];
      const float sv3 = (l15 == 15) ? accS[3][r] : NEG_INF;
      float m = fmaxf(fmaxf(sv0, sv1), fmaxf(sv2, sv3));
      m = fmaxf(m, __shfl_xor(m, 1));
      m = fmaxf(m, __shfl_xor(m, 2));
      m = fmaxf(m, __shfl_xor(m, 4));
      m = fmaxf(m, __shfl_xor(m, 8));
      const float e0 = __expf(sv0 - m);
      const float e1 = __expf(sv1 - m);
      const float e2 = __expf(sv2 - m);
      const float e3 = __expf(sv3 - m);
      float s = e0 + e1 + e2 + e3;
      s += __shfl_xor(s, 1);
      s += __shfl_xor(s, 2);
      s += __shfl_xor(s, 4);
      s += __shfl_xor(s, 8);
      const float inv = 1.0f / s;
      s_p[row * 64 + swzi(row, 0  + l15)] = (__bf16)(e0 * inv);
      s_p[row * 64 + swzi(row, 16 + l15)] = (__bf16)(e1 * inv);
      s_p[row * 64 + swzi(row, 32 + l15)] = (__bf16)(e2 * inv);
      if (l15 == 15) s_p[row * 64 + swzi(row, 48)] = (__bf16)(e3 * inv);
      if (l15 < 15)  s_p[row * 64 + swzi(row, 49 + l15)] = (__bf16)0.0f;
    }
    bf16x8 ap[2], bv2[4][2];
#pragma unroll
    for (int ks2 = 0; ks2 < 2; ++ks2) {
      const int row = R + l15;
      ap[ks2] = *(const bf16x8*)&s_p[row * 64 + swzi(row, ks2 * 32 + kg)];
    }
#pragma unroll
    for (int nt = 0; nt < 4; ++nt) {
      const int row = nt * 16 + l15;
#pragma unroll
      for (int ks2 = 0; ks2 < 2; ++ks2)
        bv2[nt][ks2] = *(const bf16x8*)&s_vT[row * 64 + swzi(row, ks2 * 32 + kg)];
    }
    __syncthreads();
    f32x4 accO[4];
#pragma unroll
    for (int n = 0; n < 4; ++n) accO[n] = zf;
#pragma unroll
    for (int ks2 = 0; ks2 < 2; ++ks2)
#pragma unroll
      for (int nt = 0; nt < 4; ++nt)
        accO[nt] = MFMA_BF16(ap[ks2], bv2[nt][ks2], accO[nt]);
#pragma unroll
    for (int nt = 0; nt < 4; ++nt) {
#pragma unroll
      for (int r = 0; r < 4; ++r) {
        const int row = R + r4 + r;
        s_p[row * 64 + swzi(row, nt * 16 + l15)] = (__bf16)accO[nt][r];
      }
    }
    __syncthreads();
#pragma unroll
    for (int ks2 = 0; ks2 < 2; ++ks2) {
      bf16x8 ao[4], bw[8];
#pragma unroll
      for (int mt = 0; mt < 4; ++mt) {
        const int row = MOFF[mt] + l15;
        ao[mt] = *(const bf16x8*)&s_p[row * 64 + swzi(row, ks2 * 32 + kg)];
      }
#pragma unroll
      for (int nt = 0; nt < 8; ++nt) {
        const int cc = wv * 128 + nt * 16 + l15;
        bw[nt] = *(const bf16x8*)(wproj_bf + (size_t)cc * 512 + h * 64 + ks2 * 32 + kg);
      }
#pragma unroll
      for (int mt = 0; mt < 4; ++mt)
#pragma unroll
        for (int nt = 0; nt < 8; ++nt)
          accF[mt][nt] = MFMA_BF16(ao[mt], bw[nt], accF[mt][nt]);
    }
  }
#pragma unroll
  for (int nt = 0; nt < 8; ++nt) {
    const int cc = wv * 128 + nt * 16 + l15;
    const float bp = bproj[cc];
#pragma unroll
    for (int mt = 0; mt < 4; ++mt) {
#pragma unroll
      for (int r = 0; r < 4; ++r) {
        const int row = MOFF[mt] + r4 + r;
        if (mt < 3 || (r4 + r) == 15) {
          out[((size_t)b * 50176 + (size_t)row * 1024 + (size_t)wi) * 512 + cc] =
              accF[mt][nt][r] + bp;
        }
      }
    }
  }
}

// ---------------------------------------------------------------------------
extern "C" void kernel_launch(void* const* d_in, const int* in_sizes, int n_in,
                              void* d_out, int out_size, void* d_ws, size_t ws_size,
                              hipStream_t stream) {
  const float* x      = (const float*)d_in[0];
  const float* w_qkv  = (const float*)d_in[1];
  const float* b_qkv  = (const float*)d_in[2];
  const float* w_proj = (const float*)d_in[3];
  const float* b_proj = (const float*)d_in[4];
  float* outp = (float*)d_out;

  const size_t QKV_E = (size_t)200704 * 1536;
  const size_t O_E   = (size_t)200704 * 512;
  const size_t NEED  = (QKV_E + O_E + 786432 + 262144) * 2 + 1536 * 4;

  if (ws_size >= NEED) {
    __bf16* qkv      = (__bf16*)d_ws;
    __bf16* Obuf     = qkv + QKV_E;      // holds x_bf16 first, then attn output
    __bf16* wqkv_bf  = Obuf + O_E;
    __bf16* wproj_bf = wqkv_bf + 786432;
    float*  bq_s     = (float*)(wproj_bf + 262144);

    prep_weights<<<512, 256, 0, stream>>>(w_qkv, b_qkv, w_proj, wqkv_bf, wproj_bf, bq_s);
    prep_x<<<2048, 256, 0, stream>>>(x, Obuf);                       // x -> bf16
    gemm_bt<false><<<1568 * 12, 256, 0, stream>>>(Obuf, wqkv_bf, bq_s, qkv, 1568, 12);
    attn_win<<<4096, 512, 0, stream>>>(qkv, Obuf);                   // overwrites x_bf16
    gemm_bt<true ><<<1568 * 4,  256, 0, stream>>>(Obuf, wproj_bf, b_proj, outp, 1568, 4);
  } else {
    __bf16* wqkv_bf  = (__bf16*)d_ws;
    __bf16* wproj_bf = wqkv_bf + 1536 * 512;
    float*  bq_s     = (float*)(wproj_bf + 512 * 512);
    prep_weights<<<1024, 256, 0, stream>>>(w_qkv, b_qkv, w_proj, wqkv_bf, wproj_bf, bq_s);
    swin_attn_fused<<<4096, 256, 0, stream>>>(x, wqkv_bf, bq_s, wproj_bf, b_proj, outp);
  }
}

// Round 5
// 1138.090 us; speedup vs baseline: 2.8385x; 1.0158x over previous
//
#include <hip/hip_runtime.h>
#include <cstdint>
#include <cstddef>

// ---------------------------------------------------------------------------
// ShuffleWindowAttention, MI355X (gfx950)
// B=4, N=50176, C=512, WS=49, w=1024 windows/batch, NH=8, hd=64
// Pipeline: prep_weights + prep_x (fp32->bf16) -> QKV GEMM (256^2 tile,
// counted-vmcnt schedule) -> windowed attention -> proj GEMM (same template).
// x_bf16 lives in the O buffer slot (dead by the time attn overwrites it).
// ---------------------------------------------------------------------------

typedef __bf16 bf16x8 __attribute__((ext_vector_type(8)));
typedef __bf16 bf16x4 __attribute__((ext_vector_type(4)));
typedef float  f32x4  __attribute__((ext_vector_type(4)));

#define MFMA_BF16(a, b, c) __builtin_amdgcn_mfma_f32_16x16x32_bf16((a), (b), (c), 0, 0, 0)

static __device__ __forceinline__ int swzi(int row, int col) {
  return col ^ ((row & 7) << 3);   // attn kernels' swizzle (128B rows)
}

typedef __attribute__((address_space(1))) const void gconst_t;
typedef __attribute__((address_space(3))) void lds_t;
static __device__ __forceinline__ void gload16(const void* g, void* l) {
  __builtin_amdgcn_global_load_lds((gconst_t*)g, (lds_t*)l, 16, 0, 0);
}

#define RAW_BAR()  asm volatile("s_barrier" ::: "memory")
#define WAITV(N)   asm volatile("s_waitcnt vmcnt(" #N ")" ::: "memory")

// ---------------------------------------------------------------------------
__global__ void prep_weights(const float* __restrict__ wqkv,
                             const float* __restrict__ bqkv,
                             const float* __restrict__ wproj,
                             __bf16* __restrict__ wqkv_bf,
                             __bf16* __restrict__ wproj_bf,
                             float* __restrict__ bq_s) {
  const int stride = gridDim.x * blockDim.x;
  const int t0 = blockIdx.x * blockDim.x + threadIdx.x;
  for (int i = t0; i < 1536 * 512; i += stride) {
    float v = wqkv[i];
    if (i < 512 * 512) v *= 0.125f;
    wqkv_bf[i] = (__bf16)v;
  }
  for (int i = t0; i < 512 * 512; i += stride) wproj_bf[i] = (__bf16)wproj[i];
  for (int i = t0; i < 1536; i += stride)      bq_s[i] = (i < 512 ? 0.125f : 1.0f) * bqkv[i];
}

// x: fp32 [200704*512] -> bf16
__global__ void prep_x(const float* __restrict__ x, __bf16* __restrict__ xb) {
  const size_t total  = (size_t)200704 * 512 / 8;
  const size_t stride = (size_t)gridDim.x * blockDim.x;
  for (size_t i = (size_t)blockIdx.x * blockDim.x + threadIdx.x; i < total; i += stride) {
    const float4 a = *(const float4*)(x + i * 8);
    const float4 b = *(const float4*)(x + i * 8 + 4);
    bf16x8 t;
    t[0] = (__bf16)a.x; t[1] = (__bf16)a.y; t[2] = (__bf16)a.z; t[3] = (__bf16)a.w;
    t[4] = (__bf16)b.x; t[5] = (__bf16)b.y; t[6] = (__bf16)b.z; t[7] = (__bf16)b.w;
    *(bf16x8*)(xb + i * 8) = t;
  }
}

// ---------------------------------------------------------------------------
// 256x256-tile GEMM: C[M][N] = A[M][512] @ B[N][512]^T + bias.
// 512 thr = 8 waves (2M x 4N), BK=64, K=512 -> 8 K-tiles, LDS 128 KiB dbuf.
// Counted-vmcnt schedule: per K-tile {bar; issue 8 gload_lds(next);
// vmcnt(8); bar; 24 ds_read + 128 MFMA}. vmcnt never 0 in the main loop.
// LDS chunk-XOR swizzle: phys chunk p holds global chunk p^(row&7);
// staging pre-swizzles the GLOBAL source column, dest stays lane-linear.
// ---------------------------------------------------------------------------
template<bool OUT_F32>
__launch_bounds__(512, 1)
__global__ void gemm256(const __bf16* __restrict__ Ab,   // [M][512]
                        const __bf16* __restrict__ Bw,   // [N][512]
                        const float* __restrict__ bias,  // [N]
                        void* __restrict__ Cv,
                        int Mtiles, int Ntiles) {
  __shared__ __align__(16) __bf16 sA[2][256 * 64];
  __shared__ __align__(16) __bf16 sB[2][256 * 64];

  const int tid  = threadIdx.x;
  const int lane = tid & 63;
  const int l15  = lane & 15;
  const int kgc  = (lane >> 4) & 3;     // k-chunk within 32-k slice
  const int r4   = kgc * 4;             // C/D row group
  const int wv   = tid >> 6;            // 0..7
  const int wm   = wv >> 2, wn = wv & 3;

  const int nwg = Mtiles * Ntiles;
  const int cpx = nwg >> 3;                       // nwg % 8 == 0
  const int wg  = (blockIdx.x & 7) * cpx + (blockIdx.x >> 3);
  const int mt  = wg / Ntiles;                    // M-outer: A-tile L2 reuse
  const int nt  = wg % Ntiles;
  const size_t m0 = (size_t)mt * 256;
  const int    n0 = nt * 256;

  // staging: per issue j (0..3), thread covers row j*64+(tid>>3);
  // phys chunk = tid&7, global chunk = (tid&7)^(row&7)
  const int srow   = tid >> 3;                    // 0..63
  const int schunk = (tid & 7) ^ (srow & 7);

  f32x4 acc[8][4];
  const f32x4 zf = {0.f, 0.f, 0.f, 0.f};
#pragma unroll
  for (int i = 0; i < 8; ++i)
#pragma unroll
    for (int j = 0; j < 4; ++j) acc[i][j] = zf;

  auto STAGE = [&](int bufi, int kt) {
    const size_t kof = (size_t)kt * 64 + schunk * 8;
#pragma unroll
    for (int j = 0; j < 4; ++j) {
      gload16(Ab + (m0 + (size_t)(j * 64 + srow)) * 512 + kof,
              &sA[bufi][0] + j * 4096 + tid * 8);
      gload16(Bw + ((size_t)(n0 + j * 64 + srow)) * 512 + kof,
              &sB[bufi][0] + j * 4096 + tid * 8);
    }
  };

  auto COMPUTE = [&](int bufi) {
#pragma unroll
    for (int ks = 0; ks < 2; ++ks) {
      bf16x8 bfrag[4];
#pragma unroll
      for (int n = 0; n < 4; ++n) {
        const int r = wn * 64 + n * 16 + l15;
        bfrag[n] = *(const bf16x8*)&sB[bufi][r * 64 + (((ks * 4 + kgc) ^ (r & 7)) * 8)];
      }
#pragma unroll
      for (int mh = 0; mh < 2; ++mh) {
        bf16x8 afrag[4];
#pragma unroll
        for (int m2 = 0; m2 < 4; ++m2) {
          const int r = wm * 128 + mh * 64 + m2 * 16 + l15;
          afrag[m2] = *(const bf16x8*)&sA[bufi][r * 64 + (((ks * 4 + kgc) ^ (r & 7)) * 8)];
        }
        __builtin_amdgcn_s_setprio(1);
#pragma unroll
        for (int m2 = 0; m2 < 4; ++m2)
#pragma unroll
          for (int n = 0; n < 4; ++n)
            acc[mh * 4 + m2][n] = MFMA_BF16(afrag[m2], bfrag[n], acc[mh * 4 + m2][n]);
        __builtin_amdgcn_s_setprio(0);
      }
    }
  };

  // prologue: K-tile 0 -> buf 0 (8 loads in flight)
  STAGE(0, 0);

  for (int tt = 0; tt < 8; tt += 2) {
    // ---- tile tt (even), compute buf 0 ----
    RAW_BAR();                 // all waves done reading buf1 (prev odd tile)
    STAGE(1, tt + 1);          // tt+1 <= 7 always
    WAITV(8);                  // own tile-tt loads (oldest 8) complete
    RAW_BAR();                 // => ALL waves' tile-tt loads complete
    COMPUTE(0);

    // ---- tile tt+1 (odd), compute buf 1 ----
    RAW_BAR();                 // all waves done reading buf0
    if (tt < 6) {
      STAGE(0, tt + 2);
      WAITV(8);
    } else {
      WAITV(0);                // last tile: drain remaining 8
    }
    RAW_BAR();
    COMPUTE(1);
  }

  // ---- epilogue ----
  const int Nld = Ntiles * 256;
#pragma unroll
  for (int n = 0; n < 4; ++n) {
    const int col = n0 + wn * 64 + n * 16 + l15;
    const float bb = bias[col];
#pragma unroll
    for (int m = 0; m < 8; ++m) {
#pragma unroll
      for (int r = 0; r < 4; ++r) {
        const size_t row = m0 + wm * 128 + m * 16 + r4 + r;
        const float v = acc[m][n][r] + bb;
        if (OUT_F32) ((float*)Cv)[row * (size_t)Nld + col] = v;
        else         ((__bf16*)Cv)[row * (size_t)Nld + col] = (__bf16)v;
      }
    }
  }
}

// ---------------------------------------------------------------------------
// Windowed attention: one block (8 waves) per window, wave = head.
// qkv[token][1536] bf16 in;  O[token][512] bf16 out.
// ---------------------------------------------------------------------------
__launch_bounds__(512)
__global__ void attn_win(const __bf16* __restrict__ qkv, __bf16* __restrict__ O) {
  __shared__ __align__(16) __bf16 vT[8 * 64 * 64];   // [h][n][k ^ swz(n)]
  __shared__ __align__(16) __bf16 sP[8][16 * 64];    // per-wave P tile

  const int tid  = threadIdx.x;
  const int lane = tid & 63;
  const int h    = tid >> 6;                 // wave = head
  const int l15  = lane & 15;
  const int kg   = ((lane >> 4) & 3) * 8;
  const int r4   = ((lane >> 4) & 3) * 4;

  const int blk = blockIdx.x;
  const int b   = blk >> 10;
  const int wi  = blk & 1023;
  const size_t tokbase = (size_t)b * 50176 + wi;   // token(s) = tokbase + s*1024

  const int MOFF[4] = {0, 16, 32, 33};
  const float NEG_INF = -__builtin_inff();

  // ---- issue q,k fragment loads early (overlap with V staging) ----
  bf16x8 aq[4][2], bk[4][2];
#pragma unroll
  for (int mt = 0; mt < 4; ++mt) {
    const size_t tok = tokbase + (size_t)(MOFF[mt] + l15) * 1024;
#pragma unroll
    for (int ks = 0; ks < 2; ++ks) {
      aq[mt][ks] = *(const bf16x8*)(qkv + tok * 1536 +       h * 64 + ks * 32 + kg);
      bk[mt][ks] = *(const bf16x8*)(qkv + tok * 1536 + 512 + h * 64 + ks * 32 + kg);
    }
  }

  // ---- zero vT pad rows k = 49..63 ----
  for (int i = tid; i < 8 * 64 * 16; i += 512) {
    const int k = 48 + (i & 15);
    if (k != 48) {
      const int n  = (i >> 4) & 63;
      const int hh = i >> 10;
      vT[hh * 4096 + n * 64 + (k ^ ((n & 7) << 3))] = (__bf16)0.0f;
    }
  }
  // ---- stage V transposed (+swizzled) ----
  for (int i = tid; i < 49 * 64; i += 512) {
    const int s  = i >> 6;
    const int c8 = (i & 63) * 8;
    bf16x8 v8 = *(const bf16x8*)(qkv + (tokbase + (size_t)s * 1024) * 1536 + 1024 + c8);
    const int hh = c8 >> 6;
#pragma unroll
    for (int j = 0; j < 8; ++j) {
      const int n = (c8 & 63) + j;
      vT[hh * 4096 + n * 64 + (s ^ ((n & 7) << 3))] = v8[j];
    }
  }
  __syncthreads();

  // ---- V fragments (conflict-free via swizzle) ----
  bf16x8 bv[4][2];
#pragma unroll
  for (int ntv = 0; ntv < 4; ++ntv) {
    const int n = ntv * 16 + l15;
#pragma unroll
    for (int ks = 0; ks < 2; ++ks)
      bv[ntv][ks] = *(const bf16x8*)&vT[h * 4096 + n * 64 + ((ks * 32 + kg) ^ ((n & 7) << 3))];
  }

  // ---- S = q k^T ----
  f32x4 accS[4][4];
  const f32x4 zf = {0.f, 0.f, 0.f, 0.f};
#pragma unroll
  for (int m = 0; m < 4; ++m)
#pragma unroll
    for (int n = 0; n < 4; ++n) accS[m][n] = zf;
#pragma unroll
  for (int ks = 0; ks < 2; ++ks)
#pragma unroll
    for (int m = 0; m < 4; ++m)
#pragma unroll
      for (int n = 0; n < 4; ++n)
        accS[m][n] = MFMA_BF16(aq[m][ks], bk[n][ks], accS[m][n]);

  // ---- per row-tile: softmax -> P (LDS) -> PV -> store O ----
#pragma unroll
  for (int mt = 0; mt < 4; ++mt) {
#pragma unroll
    for (int r = 0; r < 4; ++r) {
      const int prow = r4 + r;
      const float sv0 = accS[mt][0][r];
      const float sv1 = accS[mt][1][r];
      const float sv2 = accS[mt][2][r];
      const float sv3 = (l15 == 15) ? accS[mt][3][r] : NEG_INF;
      float mx = fmaxf(fmaxf(sv0, sv1), fmaxf(sv2, sv3));
      mx = fmaxf(mx, __shfl_xor(mx, 1));
      mx = fmaxf(mx, __shfl_xor(mx, 2));
      mx = fmaxf(mx, __shfl_xor(mx, 4));
      mx = fmaxf(mx, __shfl_xor(mx, 8));
      const float e0 = __expf(sv0 - mx);
      const float e1 = __expf(sv1 - mx);
      const float e2 = __expf(sv2 - mx);
      const float e3 = __expf(sv3 - mx);      // 0 for masked lanes
      float sum = e0 + e1 + e2 + e3;
      sum += __shfl_xor(sum, 1);
      sum += __shfl_xor(sum, 2);
      sum += __shfl_xor(sum, 4);
      sum += __shfl_xor(sum, 8);
      const float inv = 1.0f / sum;
      sP[h][prow * 64 + swzi(prow, 0  + l15)] = (__bf16)(e0 * inv);
      sP[h][prow * 64 + swzi(prow, 16 + l15)] = (__bf16)(e1 * inv);
      sP[h][prow * 64 + swzi(prow, 32 + l15)] = (__bf16)(e2 * inv);
      if (l15 == 15) sP[h][prow * 64 + swzi(prow, 48)] = (__bf16)(e3 * inv);
      if (l15 < 15)  sP[h][prow * 64 + swzi(prow, 49 + l15)] = (__bf16)0.0f;
    }
    bf16x8 ap[2];
#pragma unroll
    for (int ks = 0; ks < 2; ++ks)
      ap[ks] = *(const bf16x8*)&sP[h][l15 * 64 + swzi(l15, ks * 32 + kg)];
    f32x4 accO[4];
#pragma unroll
    for (int n = 0; n < 4; ++n) accO[n] = zf;
#pragma unroll
    for (int ks = 0; ks < 2; ++ks)
#pragma unroll
      for (int n = 0; n < 4; ++n)
        accO[n] = MFMA_BF16(ap[ks], bv[n][ks], accO[n]);
#pragma unroll
    for (int n = 0; n < 4; ++n) {
#pragma unroll
      for (int r = 0; r < 4; ++r) {
        const int row = MOFF[mt] + r4 + r;
        O[(tokbase + (size_t)row * 1024) * 512 + h * 64 + n * 16 + l15] =
            (__bf16)accO[n][r];
      }
    }
  }
}

// ===========================================================================
// Fallback: round-1 fused kernel (used only if ws_size is too small).
// ===========================================================================
__launch_bounds__(256, 2)
__global__ void swin_attn_fused(const float* __restrict__ x,
                                const __bf16* __restrict__ wqkv_bf,
                                const float* __restrict__ bq_s,
                                const __bf16* __restrict__ wproj_bf,
                                const float* __restrict__ bproj,
                                float* __restrict__ out) {
  __shared__ __align__(16) __bf16 s_xw[49 * 512];
  __shared__ __align__(16) __bf16 s_q [49 * 64];
  __shared__ __align__(16) __bf16 s_k [49 * 64];
  __shared__ __align__(16) __bf16 s_vT[64 * 64];
  __shared__ __align__(16) __bf16 s_p [49 * 64];

  const int tid  = threadIdx.x;
  const int lane = tid & 63;
  const int wv   = tid >> 6;
  const int l15  = lane & 15;
  const int kg   = (lane >> 4) * 8;
  const int r4   = (lane >> 4) * 4;
  const int blk = blockIdx.x;
  const int b   = blk >> 10;
  const int wi  = blk & 1023;
  const int MOFF[4] = {0, 16, 32, 33};
  const float NEG_INF = -__builtin_inff();

  for (int i = tid; i < 64 * 64; i += 256) s_vT[i] = (__bf16)0.0f;
  const float* xwin = x + ((size_t)b * 50176 + (size_t)wi) * 512;
  for (int idx = tid; idx < 49 * 128; idx += 256) {
    const int row = idx >> 7;
    const int c4  = (idx & 127) * 4;
    const float4 v = *(const float4*)(xwin + (size_t)row * (1024 * 512) + c4);
    bf16x4 t;
    t.x = (__bf16)v.x; t.y = (__bf16)v.y; t.z = (__bf16)v.z; t.w = (__bf16)v.w;
    *(bf16x4*)&s_xw[row * 512 + swzi(row, c4)] = t;
  }
  f32x4 accF[4][8];
  const f32x4 zf = {0.f, 0.f, 0.f, 0.f};
#pragma unroll
  for (int m = 0; m < 4; ++m)
#pragma unroll
    for (int n = 0; n < 8; ++n) accF[m][n] = zf;
  __syncthreads();

  for (int h = 0; h < 8; ++h) {
    f32x4 accA[4][3];
#pragma unroll
    for (int m = 0; m < 4; ++m)
#pragma unroll
      for (int n = 0; n < 3; ++n) accA[m][n] = zf;
    const __bf16* pB[3];
    float biasv[3];
#pragma unroll
    for (int nt = 0; nt < 3; ++nt) {
      const int c  = wv * 48 + nt * 16 + l15;
      const int wr = (c < 64) ? (h * 64 + c)
                   : (c < 128) ? (512 + h * 64 + (c - 64))
                               : (1024 + h * 64 + (c - 128));
      pB[nt]    = wqkv_bf + (size_t)wr * 512 + kg;
      biasv[nt] = bq_s[wr];
    }
#pragma unroll
    for (int ks = 0; ks < 16; ++ks) {
      bf16x8 a[4], bb[3];
#pragma unroll
      for (int mt = 0; mt < 4; ++mt) {
        const int row = MOFF[mt] + l15;
        a[mt] = *(const bf16x8*)&s_xw[row * 512 + swzi(row, ks * 32 + kg)];
      }
#pragma unroll
      for (int nt = 0; nt < 3; ++nt) bb[nt] = *(const bf16x8*)(pB[nt] + ks * 32);
#pragma unroll
      for (int mt = 0; mt < 4; ++mt)
#pragma unroll
        for (int nt = 0; nt < 3; ++nt)
          accA[mt][nt] = MFMA_BF16(a[mt], bb[nt], accA[mt][nt]);
    }
#pragma unroll
    for (int nt = 0; nt < 3; ++nt) {
      const int c = wv * 48 + nt * 16 + l15;
#pragma unroll
      for (int mt = 0; mt < 4; ++mt) {
#pragma unroll
        for (int r = 0; r < 4; ++r) {
          const int row = MOFF[mt] + r4 + r;
          const __bf16 bvv = (__bf16)(accA[mt][nt][r] + biasv[nt]);
          if (c < 64)       s_q[row * 64 + swzi(row, c)] = bvv;
          else if (c < 128) s_k[row * 64 + swzi(row, c - 64)] = bvv;
          else {
            const int vr = c - 128;
            s_vT[vr * 64 + swzi(vr, row)] = bvv;
          }
        }
      }
    }
    __syncthreads();

    const int R = MOFF[wv];
    bf16x8 aq[2], bkf[4][2];
#pragma unroll
    for (int ks2 = 0; ks2 < 2; ++ks2) {
      const int row = R + l15;
      aq[ks2] = *(const bf16x8*)&s_q[row * 64 + swzi(row, ks2 * 32 + kg)];
    }
#pragma unroll
    for (int nt = 0; nt < 4; ++nt) {
      const int row = MOFF[nt] + l15;
#pragma unroll
      for (int ks2 = 0; ks2 < 2; ++ks2)
        bkf[nt][ks2] = *(const bf16x8*)&s_k[row * 64 + swzi(row, ks2 * 32 + kg)];
    }
    f32x4 accS[4];
#pragma unroll
    for (int n = 0; n < 4; ++n) accS[n] = zf;
#pragma unroll
    for (int ks2 = 0; ks2 < 2; ++ks2)
#pragma unroll
      for (int nt = 0; nt < 4; ++nt)
        accS[nt] = MFMA_BF16(aq[ks2], bkf[nt][ks2], accS[nt]);
#pragma unroll
    for (int r = 0; r < 4; ++r) {
      const int row = R + r4 + r;
      const float sv0 = accS[0][r];
      const float sv1 = accS[1][r];
      const float sv2 = accS[2][r];
      const float sv3 = (l15 == 15) ? accS[3][r] : NEG_INF;
      float m = fmaxf(fmaxf(sv0, sv1), fmaxf(sv2, sv3));
      m = fmaxf(m, __shfl_xor(m, 1));
      m = fmaxf(m, __shfl_xor(m, 2));
      m = fmaxf(m, __shfl_xor(m, 4));
      m = fmaxf(m, __shfl_xor(m, 8));
      const float e0 = __expf(sv0 - m);
      const float e1 = __expf(sv1 - m);
      const float e2 = __expf(sv2 - m);
      const float e3 = __expf(sv3 - m);
      float s = e0 + e1 + e2 + e3;
      s += __shfl_xor(s, 1);
      s += __shfl_xor(s, 2);
      s += __shfl_xor(s, 4);
      s += __shfl_xor(s, 8);
      const float inv = 1.0f / s;
      s_p[row * 64 + swzi(row, 0  + l15)] = (__bf16)(e0 * inv);
      s_p[row * 64 + swzi(row, 16 + l15)] = (__bf16)(e1 * inv);
      s_p[row * 64 + swzi(row, 32 + l15)] = (__bf16)(e2 * inv);
      if (l15 == 15) s_p[row * 64 + swzi(row, 48)] = (__bf16)(e3 * inv);
      if (l15 < 15)  s_p[row * 64 + swzi(row, 49 + l15)] = (__bf16)0.0f;
    }
    bf16x8 ap[2], bv2[4][2];
#pragma unroll
    for (int ks2 = 0; ks2 < 2; ++ks2) {
      const int row = R + l15;
      ap[ks2] = *(const bf16x8*)&s_p[row * 64 + swzi(row, ks2 * 32 + kg)];
    }
#pragma unroll
    for (int nt = 0; nt < 4; ++nt) {
      const int row = nt * 16 + l15;
#pragma unroll
      for (int ks2 = 0; ks2 < 2; ++ks2)
        bv2[nt][ks2] = *(const bf16x8*)&s_vT[row * 64 + swzi(row, ks2 * 32 + kg)];
    }
    __syncthreads();
    f32x4 accO[4];
#pragma unroll
    for (int n = 0; n < 4; ++n) accO[n] = zf;
#pragma unroll
    for (int ks2 = 0; ks2 < 2; ++ks2)
#pragma unroll
      for (int nt = 0; nt < 4; ++nt)
        accO[nt] = MFMA_BF16(ap[ks2], bv2[nt][ks2], accO[nt]);
#pragma unroll
    for (int nt = 0; nt < 4; ++nt) {
#pragma unroll
      for (int r = 0; r < 4; ++r) {
        const int row = R + r4 + r;
        s_p[row * 64 + swzi(row, nt * 16 + l15)] = (__bf16)accO[nt][r];
      }
    }
    __syncthreads();
#pragma unroll
    for (int ks2 = 0; ks2 < 2; ++ks2) {
      bf16x8 ao[4], bw[8];
#pragma unroll
      for (int mt = 0; mt < 4; ++mt) {
        const int row = MOFF[mt] + l15;
        ao[mt] = *(const bf16x8*)&s_p[row * 64 + swzi(row, ks2 * 32 + kg)];
      }
#pragma unroll
      for (int nt = 0; nt < 8; ++nt) {
        const int cc = wv * 128 + nt * 16 + l15;
        bw[nt] = *(const bf16x8*)(wproj_bf + (size_t)cc * 512 + h * 64 + ks2 * 32 + kg);
      }
#pragma unroll
      for (int mt = 0; mt < 4; ++mt)
#pragma unroll
        for (int nt = 0; nt < 8; ++nt)
          accF[mt][nt] = MFMA_BF16(ao[mt], bw[nt], accF[mt][nt]);
    }
  }
#pragma unroll
  for (int nt = 0; nt < 8; ++nt) {
    const int cc = wv * 128 + nt * 16 + l15;
    const float bp = bproj[cc];
#pragma unroll
    for (int mt = 0; mt < 4; ++mt) {
#pragma unroll
      for (int r = 0; r < 4; ++r) {
        const int row = MOFF[mt] + r4 + r;
        if (mt < 3 || (r4 + r) == 15) {
          out[((size_t)b * 50176 + (size_t)row * 1024 + (size_t)wi) * 512 + cc] =
              accF[mt][nt][r] + bp;
        }
      }
    }
  }
}

// ---------------------------------------------------------------------------
extern "C" void kernel_launch(void* const* d_in, const int* in_sizes, int n_in,
                              void* d_out, int out_size, void* d_ws, size_t ws_size,
                              hipStream_t stream) {
  const float* x      = (const float*)d_in[0];
  const float* w_qkv  = (const float*)d_in[1];
  const float* b_qkv  = (const float*)d_in[2];
  const float* w_proj = (const float*)d_in[3];
  const float* b_proj = (const float*)d_in[4];
  float* outp = (float*)d_out;

  const size_t QKV_E = (size_t)200704 * 1536;
  const size_t O_E   = (size_t)200704 * 512;
  const size_t NEED  = (QKV_E + O_E + 786432 + 262144) * 2 + 1536 * 4;

  if (ws_size >= NEED) {
    __bf16* qkv      = (__bf16*)d_ws;
    __bf16* Obuf     = qkv + QKV_E;      // holds x_bf16 first, then attn output
    __bf16* wqkv_bf  = Obuf + O_E;
    __bf16* wproj_bf = wqkv_bf + 786432;
    float*  bq_s     = (float*)(wproj_bf + 262144);

    prep_weights<<<512, 256, 0, stream>>>(w_qkv, b_qkv, w_proj, wqkv_bf, wproj_bf, bq_s);
    prep_x<<<2048, 256, 0, stream>>>(x, Obuf);                       // x -> bf16
    // QKV: M=200704 (784 tiles), N=1536 (6 tiles)
    gemm256<false><<<784 * 6, 512, 0, stream>>>(Obuf, wqkv_bf, bq_s, qkv, 784, 6);
    attn_win<<<4096, 512, 0, stream>>>(qkv, Obuf);                   // overwrites x_bf16
    // proj: M=200704 (784 tiles), N=512 (2 tiles)
    gemm256<true ><<<784 * 2, 512, 0, stream>>>(Obuf, wproj_bf, b_proj, outp, 784, 2);
  } else {
    __bf16* wqkv_bf  = (__bf16*)d_ws;
    __bf16* wproj_bf = wqkv_bf + 1536 * 512;
    float*  bq_s     = (float*)(wproj_bf + 512 * 512);
    prep_weights<<<1024, 256, 0, stream>>>(w_qkv, b_qkv, w_proj, wqkv_bf, wproj_bf, bq_s);
    swin_attn_fused<<<4096, 256, 0, stream>>>(x, wqkv_bf, bq_s, wproj_bf, b_proj, outp);
  }
}